// Round 1
// baseline (7000.241 us; speedup 1.0000x reference)
//
#include <hip/hip_runtime.h>
#include <hip/hip_bf16.h>
#include <cfloat>
#include <cstdint>

// ---------------------------------------------------------------------------
// RPN pipeline (B=1): conv3d(256->512,3x3x3,SAME)+ReLU -> heads -> proposals
// Shapes: base_feat (1,256,16,32,32), H=W=32, T=16
// Outputs: rois (1,128,7), rois16 (1,128,5), 4 scalar zeros -> 1540 floats
// ---------------------------------------------------------------------------

#define T_DIM 16
#define H_DIM 32
#define W_DIM 32
#define NVOX  (T_DIM*H_DIM*W_DIM)   // 16384
#define HW    (H_DIM*W_DIM)         // 1024
#define CIN   256
#define COUT  512
#define PRE_NMS 1000
#define POST_NMS 128
#define NMS_TH 0.7f

// anchor tables: ratios (0.5,1.0,2.0) -> (ws,hs) = (23,12),(16,16),(11,22); scales 4,8,16
__constant__ float c_ws[3] = {23.f, 16.f, 11.f};
__constant__ float c_hs[3] = {12.f, 16.f, 22.f};
__constant__ float c_sc[3] = {4.f, 8.f, 16.f};
__constant__ float c_depth[3] = {16.f, 8.f, 4.f};

// ---------------------------------------------------------------------------
// Weight transpose: Wt[tap][c][o] = W[o][c][tap]
__global__ void k_transpose_w(const float* __restrict__ W, float* __restrict__ Wt) {
    int i = blockIdx.x * 256 + threadIdx.x;   // over 27*256*512 = 3538944
    int o = i & 511;
    int c = (i >> 9) & 255;
    int tap = i >> 17;
    Wt[i] = W[(o * 256 + c) * 27 + tap];
}

// Wcomb[c][o'] : o'<54 = W_cls[o'][c]; 54..215 = W_bbox[o'-54][c]; 216..255 = 0
__global__ void k_build_wcomb(const float* __restrict__ Wcls, const float* __restrict__ Wbb,
                              float* __restrict__ Wc) {
    int i = blockIdx.x * 256 + threadIdx.x;   // over 512*256
    int o = i & 255;
    int c = i >> 8;
    float v = 0.f;
    if (o < 54) v = Wcls[o * 512 + c];
    else if (o < 216) v = Wbb[(o - 54) * 512 + c];
    Wc[i] = v;
}

// ---------------------------------------------------------------------------
// conv3d as implicit GEMM: O[o][v] = relu(bias[o] + sum_{tap,c} Wt[tap][c][o]*I[c][shift(v,tap)])
// tile 128(o) x 128(v), 256 threads, 8x8 per thread
__global__ __launch_bounds__(256) void k_conv3d(const float* __restrict__ I,
                                                const float* __restrict__ Wt,
                                                const float* __restrict__ bias,
                                                float* __restrict__ O) {
    __shared__ float As[16][128];
    __shared__ float Bs[16][128];
    const int tid = threadIdx.x;
    const int o0 = blockIdx.y * 128;
    const int v0 = blockIdx.x * 128;
    const int ty = tid >> 4, tx = tid & 15;

    float acc[8][8];
#pragma unroll
    for (int i = 0; i < 8; i++)
#pragma unroll
        for (int j = 0; j < 8; j++) acc[i][j] = 0.f;

    const int bc_l = tid >> 4;          // B stage: c row 0..15
    const int bvs = (tid & 15) * 8;     // B stage: v start

    for (int tap = 0; tap < 27; ++tap) {
        const int kt = tap / 9 - 1, kh = (tap / 3) % 3 - 1, kw = tap % 3 - 1;
        for (int ck = 0; ck < 256; ck += 16) {
            __syncthreads();
            // stage A (weights) : coalesced float4
#pragma unroll
            for (int r = 0; r < 2; ++r) {
                int f = tid + r * 256;
                int c_l = f >> 5, o4 = (f & 31) << 2;
                const float4 w4 = *(const float4*)(Wt + ((size_t)(tap * 256 + ck + c_l) << 9) + o0 + o4);
                *(float4*)(&As[c_l][o4]) = w4;
            }
            // stage B (shifted input) : per-element with bounds check
            {
                const float* Ic = I + ((size_t)(ck + bc_l) << 14);
#pragma unroll
                for (int j = 0; j < 8; ++j) {
                    int v = v0 + bvs + j;
                    int t = v >> 10, h = (v >> 5) & 31, w = v & 31;
                    int tt = t + kt, hh = h + kh, ww = w + kw;
                    float val = 0.f;
                    if ((unsigned)tt < 16u && (unsigned)hh < 32u && (unsigned)ww < 32u)
                        val = Ic[(tt << 10) + (hh << 5) + ww];
                    Bs[bc_l][bvs + j] = val;
                }
            }
            __syncthreads();
#pragma unroll
            for (int k = 0; k < 16; ++k) {
                float a[8], b[8];
                *(float4*)(a)     = *(const float4*)(&As[k][ty * 8]);
                *(float4*)(a + 4) = *(const float4*)(&As[k][ty * 8 + 4]);
                *(float4*)(b)     = *(const float4*)(&Bs[k][tx * 8]);
                *(float4*)(b + 4) = *(const float4*)(&Bs[k][tx * 8 + 4]);
#pragma unroll
                for (int i = 0; i < 8; i++)
#pragma unroll
                    for (int j = 0; j < 8; j++)
                        acc[i][j] = fmaf(a[i], b[j], acc[i][j]);
            }
        }
    }
    // epilogue: bias + relu
#pragma unroll
    for (int i = 0; i < 8; i++) {
        int o = o0 + ty * 8 + i;
        float bo = bias[o];
        float outv[8];
#pragma unroll
        for (int j = 0; j < 8; j++) outv[j] = fmaxf(acc[i][j] + bo, 0.f);
        float* dst = O + (size_t)o * NVOX + v0 + tx * 8;
        *(float4*)(dst)     = *(const float4*)(outv);
        *(float4*)(dst + 4) = *(const float4*)(outv + 4);
    }
}

// ---------------------------------------------------------------------------
// logits3 GEMM: L[o][v] = sum_c Wc[c][o] * conv1[c][v], M=256 (padded), K=512, N=16384
__global__ __launch_bounds__(256) void k_gemm_logits3(const float* __restrict__ conv1,
                                                      const float* __restrict__ Wc,
                                                      float* __restrict__ L) {
    __shared__ float As[16][128];
    __shared__ float Bs[16][128];
    const int tid = threadIdx.x;
    const int o0 = blockIdx.y * 128;
    const int v0 = blockIdx.x * 128;
    const int ty = tid >> 4, tx = tid & 15;

    float acc[8][8];
#pragma unroll
    for (int i = 0; i < 8; i++)
#pragma unroll
        for (int j = 0; j < 8; j++) acc[i][j] = 0.f;

    for (int ck = 0; ck < 512; ck += 16) {
        __syncthreads();
#pragma unroll
        for (int r = 0; r < 2; ++r) {
            int f = tid + r * 256;
            int c_l = f >> 5, o4 = (f & 31) << 2;
            *(float4*)(&As[c_l][o4]) = *(const float4*)(Wc + ((size_t)(ck + c_l) << 8) + o0 + o4);
        }
#pragma unroll
        for (int r = 0; r < 2; ++r) {
            int f = tid + r * 256;
            int c_l = f >> 5, v4 = (f & 31) << 2;
            *(float4*)(&Bs[c_l][v4]) = *(const float4*)(conv1 + ((size_t)(ck + c_l) << 14) + v0 + v4);
        }
        __syncthreads();
#pragma unroll
        for (int k = 0; k < 16; ++k) {
            float a[8], b[8];
            *(float4*)(a)     = *(const float4*)(&As[k][ty * 8]);
            *(float4*)(a + 4) = *(const float4*)(&As[k][ty * 8 + 4]);
            *(float4*)(b)     = *(const float4*)(&Bs[k][tx * 8]);
            *(float4*)(b + 4) = *(const float4*)(&Bs[k][tx * 8 + 4]);
#pragma unroll
            for (int i = 0; i < 8; i++)
#pragma unroll
                for (int j = 0; j < 8; j++)
                    acc[i][j] = fmaf(a[i], b[j], acc[i][j]);
        }
    }
#pragma unroll
    for (int i = 0; i < 8; i++) {
        float* dst = L + (size_t)(o0 + ty * 8 + i) * NVOX + v0 + tx * 8;
        *(float4*)(dst)     = *(const float4*)(&acc[i][0]);
        *(float4*)(dst + 4) = *(const float4*)(&acc[i][4]);
    }
}

// ---------------------------------------------------------------------------
// sc3[hw*27+a] = mean_t softmax-fg of (L[a]+b[a], L[27+a]+b[27+a])
__global__ void k_sc3(const float* __restrict__ L, const float* __restrict__ b_cls,
                      float* __restrict__ sc3) {
    int i = blockIdx.x * 256 + threadIdx.x;   // 27648
    if (i >= 27 * HW) return;
    int a = i >> 10, hw = i & 1023;
    float b0 = b_cls[a], b1 = b_cls[27 + a];
    const float* L0 = L + (size_t)a * NVOX + hw;
    const float* L1 = L + (size_t)(27 + a) * NVOX + hw;
    float s = 0.f;
    for (int t = 0; t < T_DIM; t++) {
        float x0 = L0[t * HW] + b0, x1 = L1[t * HW] + b1;
        float m = fmaxf(x0, x1);
        float e0 = expf(x0 - m), e1 = expf(x1 - m);
        s += e1 / (e0 + e1);
    }
    sc3[hw * 27 + a] = s * (1.f / 16.f);
}

// dl3[(hw*27+a)*6+d] = mean_t L[54+a*6+d] + b_bbox[a*6+d]
__global__ void k_dl3(const float* __restrict__ L, const float* __restrict__ b_bbox,
                      float* __restrict__ dl3) {
    int i = blockIdx.x * 256 + threadIdx.x;   // 165888
    if (i >= 162 * HW) return;
    int ch = i >> 10, hw = i & 1023;
    const float* Lr = L + (size_t)(54 + ch) * NVOX + hw;
    float s = 0.f;
    for (int t = 0; t < T_DIM; t++) s += Lr[t * HW];
    s = s * (1.f / 16.f) + b_bbox[ch];
    int a = ch / 6, d = ch - a * 6;
    dl3[((size_t)hw * 27 + a) * 6 + d] = s;
}

// feat2[c*1024+hw] = mean_t conv1[c][t*1024+hw]
__global__ void k_feat2(const float* __restrict__ conv1, float* __restrict__ feat2) {
    int i = blockIdx.x * 256 + threadIdx.x;   // 524288
    int c = i >> 10, hw = i & 1023;
    const float* src = conv1 + (size_t)c * NVOX + hw;
    float s = 0.f;
    for (int t = 0; t < T_DIM; t++) s += src[t * HW];
    feat2[i] = s * (1.f / 16.f);
}

// L2[o*1024+hw] (o<54): rows 0..17 = W_cls16, 18..53 = W_bbox16 (no bias)
__global__ void k_gemm2d(const float* __restrict__ feat2, const float* __restrict__ Wcls16,
                         const float* __restrict__ Wbb16, float* __restrict__ L2) {
    int g = blockIdx.x * 256 + threadIdx.x;   // 55296
    int o = g >> 10, hw = g & 1023;
    const float* wrow = (o < 18) ? (Wcls16 + (size_t)o * 512) : (Wbb16 + (size_t)(o - 18) * 512);
    float s = 0.f;
    for (int c = 0; c < 512; c++) s = fmaf(wrow[c], feat2[(size_t)c * HW + hw], s);
    L2[(size_t)o * HW + hw] = s;
}

__global__ void k_sc2(const float* __restrict__ L2, const float* __restrict__ b_cls16,
                      float* __restrict__ sc2) {
    int i = blockIdx.x * 256 + threadIdx.x;   // 9216
    if (i >= 9 * HW) return;
    int a = i >> 10, hw = i & 1023;
    float x0 = L2[(size_t)a * HW + hw] + b_cls16[a];
    float x1 = L2[(size_t)(9 + a) * HW + hw] + b_cls16[9 + a];
    float m = fmaxf(x0, x1);
    float e0 = expf(x0 - m), e1 = expf(x1 - m);
    sc2[hw * 9 + a] = e1 / (e0 + e1);
}

__global__ void k_dl2(const float* __restrict__ L2, const float* __restrict__ b_bbox16,
                      float* __restrict__ dl2) {
    int i = blockIdx.x * 256 + threadIdx.x;   // 36864
    if (i >= 36 * HW) return;
    int ch = i >> 10, hw = i & 1023;
    float v = L2[(size_t)(18 + ch) * HW + hw] + b_bbox16[ch];
    int a = ch >> 2, d = ch & 3;
    dl2[((size_t)hw * 9 + a) * 4 + d] = v;
}

// ---------------------------------------------------------------------------
// proposal: top-1000 (desc value, asc index) -> decode+clip -> NMS(128) -> write rois
// blockIdx.x = 0: 3D branch (A=27, nd=3), 1: 2D branch (A=9, nd=2)
__global__ __launch_bounds__(1024) void k_proposal(const float* __restrict__ im_info,
                                                   float* __restrict__ sc3,
                                                   const float* __restrict__ dl3,
                                                   float* __restrict__ sc2,
                                                   const float* __restrict__ dl2,
                                                   float* __restrict__ out) {
    const int branch = blockIdx.x;
    const int tid = threadIdx.x;
    const int A = (branch == 0) ? 27 : 9;
    const int nd = (branch == 0) ? 3 : 2;
    float* scores = (branch == 0) ? sc3 : sc2;
    const float* deltas = (branch == 0) ? dl3 : dl2;

    __shared__ float bx[PRE_NMS][6];
    __shared__ int kidx[PRE_NMS];
    __shared__ float wv[16];
    __shared__ int wi[16];
    __shared__ int bcast;
    __shared__ int keep[POST_NMS];

    // ---- top-k with cached per-thread local maxima ----
    const int ept = A;          // elements per thread (27648/1024 or 9216/1024)
    const int base = tid * ept;
    float lv = -FLT_MAX; int li = 0x7fffffff;
    for (int j = 0; j < ept; j++) {
        float v = scores[base + j];
        if (v > lv || (v == lv && base + j < li)) { lv = v; li = base + j; }
    }

    for (int it = 0; it < PRE_NMS; ++it) {
        float v = lv; int ix = li;
#pragma unroll
        for (int off = 32; off; off >>= 1) {
            float ov = __shfl_xor(v, off);
            int oi = __shfl_xor(ix, off);
            if (ov > v || (ov == v && oi < ix)) { v = ov; ix = oi; }
        }
        if ((tid & 63) == 0) { wv[tid >> 6] = v; wi[tid >> 6] = ix; }
        __syncthreads();
        if (tid == 0) {
            float bvv = wv[0]; int bii = wi[0];
            for (int q = 1; q < 16; q++)
                if (wv[q] > bvv || (wv[q] == bvv && wi[q] < bii)) { bvv = wv[q]; bii = wi[q]; }
            bcast = bii; kidx[it] = bii;
        }
        __syncthreads();
        int widx = bcast;
        if (widx >= base && widx < base + ept) {
            scores[widx] = -FLT_MAX;
            lv = -FLT_MAX; li = 0x7fffffff;
            for (int j = 0; j < ept; j++) {
                float vv = scores[base + j];
                if (vv > lv || (vv == lv && base + j < li)) { lv = vv; li = base + j; }
            }
        }
    }
    __syncthreads();

    // ---- decode + clip ----
    const float imh = im_info[0], imw = im_info[1];
    if (tid < PRE_NMS) {
        int n = kidx[tid];
        int cell = n / A, a = n - cell * A;
        int hc = cell >> 5, wc = cell & 31;
        int a2 = (branch == 0) ? (a % 9) : a;
        int ri = a2 / 3, si = a2 % 3;
        float w = c_ws[ri] * c_sc[si], h = c_hs[ri] * c_sc[si];
        float ax0 = 7.5f - (w - 1.f) * 0.5f + 16.f * wc;
        float ay0 = 7.5f - (h - 1.f) * 0.5f + 16.f * hc;
        float ax1 = 7.5f + (w - 1.f) * 0.5f + 16.f * wc;
        float ay1 = 7.5f + (h - 1.f) * 0.5f + 16.f * hc;
        float lo[3], hi[3], mx[3];
        lo[0] = ax0; hi[0] = ax1; mx[0] = imw - 1.f;
        lo[1] = ay0; hi[1] = ay1; mx[1] = imh - 1.f;
        if (branch == 0) { lo[2] = 0.f; hi[2] = c_depth[a / 9] - 1.f; mx[2] = (float)(T_DIM - 1); }
        const float* dp = deltas + (size_t)n * (2 * nd);
        for (int d = 0; d < nd; d++) {
            float size = hi[d] - lo[d] + 1.f;
            float ctr = lo[d] + 0.5f * (size - 1.f);
            float pctr = dp[d] * size + ctr;
            float psize = expf(dp[nd + d]) * size;
            float pl = pctr - 0.5f * (psize - 1.f);
            float ph = pctr + 0.5f * (psize - 1.f);
            pl = fminf(fmaxf(pl, 0.f), mx[d]);
            ph = fminf(fmaxf(ph, 0.f), mx[d]);
            bx[tid][d] = pl;
            bx[tid][nd + d] = ph;
        }
    }
    __syncthreads();

    // ---- NMS ----
    bool supp = (tid >= PRE_NMS);
    float myb[6];
    float myvol = 1.f;
    if (tid < PRE_NMS) {
        for (int d = 0; d < 2 * nd; d++) myb[d] = bx[tid][d];
        for (int d = 0; d < nd; d++) myvol *= (myb[nd + d] - myb[d] + 1.f);
    }
    for (int i = 0; i < POST_NMS; ++i) {
        int cand = supp ? 0x7fffffff : tid;
#pragma unroll
        for (int off = 32; off; off >>= 1) {
            int oc = __shfl_xor(cand, off);
            cand = min(cand, oc);
        }
        if ((tid & 63) == 0) wi[tid >> 6] = cand;
        __syncthreads();
        if (tid == 0) {
            int m = wi[0];
            for (int q = 1; q < 16; q++) m = min(m, wi[q]);
            if (m == 0x7fffffff) m = 0;
            keep[i] = m; bcast = m;
        }
        __syncthreads();
        int sel = bcast;
        if (tid < PRE_NMS) {
            float inter = 1.f, selvol = 1.f;
            for (int d = 0; d < nd; d++) {
                float slo = bx[sel][d], shi = bx[sel][nd + d];
                float l = fmaxf(slo, myb[d]);
                float hh = fminf(shi, myb[nd + d]);
                inter *= fmaxf(hh - l + 1.f, 0.f);
                selvol *= (shi - slo + 1.f);
            }
            float iou = inter / (selvol + myvol - inter);
            if (iou > NMS_TH) supp = true;
            if (tid == sel) supp = true;
        }
        __syncthreads();
    }

    // ---- write outputs ----
    if (tid < POST_NMS) {
        int k = keep[tid];
        if (branch == 0) {
            float* o = out + (size_t)tid * 7;
            o[0] = 0.f;
            for (int d = 0; d < 6; d++) o[1 + d] = bx[k][d];
        } else {
            float* o = out + 128 * 7 + (size_t)tid * 5;
            o[0] = 0.f;
            for (int d = 0; d < 4; d++) o[1 + d] = bx[k][d];
        }
    }
    if (branch == 0 && tid == 0) {
        out[1536] = 0.f; out[1537] = 0.f; out[1538] = 0.f; out[1539] = 0.f;
    }
}

// ---------------------------------------------------------------------------
extern "C" void kernel_launch(void* const* d_in, const int* in_sizes, int n_in,
                              void* d_out, int out_size, void* d_ws, size_t ws_size,
                              hipStream_t stream) {
    (void)in_sizes; (void)n_in; (void)out_size; (void)ws_size;
    const float* base_feat = (const float*)d_in[0];
    const float* im_info   = (const float*)d_in[1];
    const float* W_conv    = (const float*)d_in[4];
    const float* b_conv    = (const float*)d_in[5];
    const float* W_cls     = (const float*)d_in[6];
    const float* b_cls     = (const float*)d_in[7];
    const float* W_bbox    = (const float*)d_in[8];
    const float* b_bbox    = (const float*)d_in[9];
    const float* W_cls16   = (const float*)d_in[10];
    const float* b_cls16   = (const float*)d_in[11];
    const float* W_bbox16  = (const float*)d_in[12];
    const float* b_bbox16  = (const float*)d_in[13];
    float* out = (float*)d_out;

    // workspace layout (bytes, all 16B aligned)
    char* ws = (char*)d_ws;
    size_t off = 0;
    float* Wt     = (float*)(ws + off); off += (size_t)27 * 256 * 512 * 4;   // 14155776
    float* Wcomb  = (float*)(ws + off); off += (size_t)512 * 256 * 4;        // 524288
    float* conv1  = (float*)(ws + off); off += (size_t)COUT * NVOX * 4;      // 33554432
    float* L3     = (float*)(ws + off); off += (size_t)256 * NVOX * 4;       // 16777216
    float* feat2  = (float*)(ws + off); off += (size_t)512 * HW * 4;         // 2097152
    float* L2     = (float*)(ws + off); off += (size_t)64 * HW * 4;          // 262144
    float* sc3    = (float*)(ws + off); off += (size_t)27 * HW * 4;          // 110592
    float* dl3    = (float*)(ws + off); off += (size_t)27 * HW * 6 * 4;      // 663552
    float* sc2    = (float*)(ws + off); off += (size_t)9 * HW * 4;           // 36864
    float* dl2    = (float*)(ws + off); off += (size_t)9 * HW * 4 * 4;       // 147456

    k_transpose_w<<<13824, 256, 0, stream>>>(W_conv, Wt);
    k_build_wcomb<<<512, 256, 0, stream>>>(W_cls, W_bbox, Wcomb);
    {
        dim3 g(NVOX / 128, COUT / 128);
        k_conv3d<<<g, 256, 0, stream>>>(base_feat, Wt, b_conv, conv1);
    }
    {
        dim3 g(NVOX / 128, 2);
        k_gemm_logits3<<<g, 256, 0, stream>>>(conv1, Wcomb, L3);
    }
    k_sc3<<<(27 * HW + 255) / 256, 256, 0, stream>>>(L3, b_cls, sc3);
    k_dl3<<<(162 * HW + 255) / 256, 256, 0, stream>>>(L3, b_bbox, dl3);
    k_feat2<<<(512 * HW) / 256, 256, 0, stream>>>(conv1, feat2);
    k_gemm2d<<<(54 * HW) / 256, 256, 0, stream>>>(feat2, W_cls16, W_bbox16, L2);
    k_sc2<<<(9 * HW + 255) / 256, 256, 0, stream>>>(L2, b_cls16, sc2);
    k_dl2<<<(36 * HW + 255) / 256, 256, 0, stream>>>(L2, b_bbox16, dl2);
    k_proposal<<<2, 1024, 0, stream>>>(im_info, sc3, dl3, sc2, dl2, out);
}

// Round 2
// 2137.550 us; speedup vs baseline: 3.2749x; 3.2749x over previous
//
#include <hip/hip_runtime.h>
#include <hip/hip_bf16.h>
#include <cfloat>
#include <cstdint>

// ---------------------------------------------------------------------------
// RPN pipeline (B=1): conv3d(256->512,3x3x3,SAME)+ReLU -> heads -> proposals
// Shapes: base_feat (1,256,16,32,32), H=W=32, T=16
// Outputs: rois (1,128,7), rois16 (1,128,5), 4 scalar zeros -> 1540 floats
// ---------------------------------------------------------------------------

#define T_DIM 16
#define H_DIM 32
#define W_DIM 32
#define NVOX  (T_DIM*H_DIM*W_DIM)   // 16384
#define HW    (H_DIM*W_DIM)         // 1024
#define CIN   256
#define COUT  512
#define PRE_NMS 1000
#define POST_NMS 128
#define NMS_TH 0.7f

// anchor tables: ratios (0.5,1.0,2.0) -> (ws,hs) = (23,12),(16,16),(11,22); scales 4,8,16
__constant__ float c_ws[3] = {23.f, 16.f, 11.f};
__constant__ float c_hs[3] = {12.f, 16.f, 22.f};
__constant__ float c_sc[3] = {4.f, 8.f, 16.f};
__constant__ float c_depth[3] = {16.f, 8.f, 4.f};

// ---------------------------------------------------------------------------
// Weight transpose: Wt[tap][c][o] = W[o][c][tap]
__global__ void k_transpose_w(const float* __restrict__ W, float* __restrict__ Wt) {
    int i = blockIdx.x * 256 + threadIdx.x;   // over 27*256*512 = 3538944
    int o = i & 511;
    int c = (i >> 9) & 255;
    int tap = i >> 17;
    Wt[i] = W[(o * 256 + c) * 27 + tap];
}

// Wcomb[c][o'] : o'<54 = W_cls[o'][c]; 54..215 = W_bbox[o'-54][c]; 216..255 = 0
__global__ void k_build_wcomb(const float* __restrict__ Wcls, const float* __restrict__ Wbb,
                              float* __restrict__ Wc) {
    int i = blockIdx.x * 256 + threadIdx.x;   // over 512*256
    int o = i & 255;
    int c = i >> 8;
    float v = 0.f;
    if (o < 54) v = Wcls[o * 512 + c];
    else if (o < 216) v = Wbb[(o - 54) * 512 + c];
    Wc[i] = v;
}

// ---------------------------------------------------------------------------
// conv3d as implicit GEMM: O[o][v] = relu(bias[o] + sum_{tap,c} Wt[tap][c][o]*I[c][shift(v,tap)])
// tile 128(o) x 128(v), 256 threads, 8x8 per thread
__global__ __launch_bounds__(256) void k_conv3d(const float* __restrict__ I,
                                                const float* __restrict__ Wt,
                                                const float* __restrict__ bias,
                                                float* __restrict__ O) {
    __shared__ float As[16][128];
    __shared__ float Bs[16][128];
    const int tid = threadIdx.x;
    const int o0 = blockIdx.y * 128;
    const int v0 = blockIdx.x * 128;
    const int ty = tid >> 4, tx = tid & 15;

    float acc[8][8];
#pragma unroll
    for (int i = 0; i < 8; i++)
#pragma unroll
        for (int j = 0; j < 8; j++) acc[i][j] = 0.f;

    const int bc_l = tid >> 4;          // B stage: c row 0..15
    const int bvs = (tid & 15) * 8;     // B stage: v start

    for (int tap = 0; tap < 27; ++tap) {
        const int kt = tap / 9 - 1, kh = (tap / 3) % 3 - 1, kw = tap % 3 - 1;
        // hoist B-address/bounds out of the ck loop (fixed per tap)
        int boff[8]; bool bval[8];
#pragma unroll
        for (int j = 0; j < 8; ++j) {
            int v = v0 + bvs + j;
            int t = v >> 10, h = (v >> 5) & 31, w = v & 31;
            int tt = t + kt, hh = h + kh, ww = w + kw;
            bval[j] = ((unsigned)tt < 16u) && ((unsigned)hh < 32u) && ((unsigned)ww < 32u);
            boff[j] = (tt << 10) + (hh << 5) + ww;
        }
        for (int ck = 0; ck < 256; ck += 16) {
            __syncthreads();
            // stage A (weights) : coalesced float4
#pragma unroll
            for (int r = 0; r < 2; ++r) {
                int f = tid + r * 256;
                int c_l = f >> 5, o4 = (f & 31) << 2;
                const float4 w4 = *(const float4*)(Wt + ((size_t)(tap * 256 + ck + c_l) << 9) + o0 + o4);
                *(float4*)(&As[c_l][o4]) = w4;
            }
            // stage B (shifted input)
            {
                const float* Ic = I + ((size_t)(ck + bc_l) << 14);
#pragma unroll
                for (int j = 0; j < 8; ++j)
                    Bs[bc_l][bvs + j] = bval[j] ? Ic[boff[j]] : 0.f;
            }
            __syncthreads();
#pragma unroll
            for (int k = 0; k < 16; ++k) {
                float a[8], b[8];
                *(float4*)(a)     = *(const float4*)(&As[k][ty * 8]);
                *(float4*)(a + 4) = *(const float4*)(&As[k][ty * 8 + 4]);
                *(float4*)(b)     = *(const float4*)(&Bs[k][tx * 8]);
                *(float4*)(b + 4) = *(const float4*)(&Bs[k][tx * 8 + 4]);
#pragma unroll
                for (int i = 0; i < 8; i++)
#pragma unroll
                    for (int j = 0; j < 8; j++)
                        acc[i][j] = fmaf(a[i], b[j], acc[i][j]);
            }
        }
    }
    // epilogue: bias + relu
#pragma unroll
    for (int i = 0; i < 8; i++) {
        int o = o0 + ty * 8 + i;
        float bo = bias[o];
        float outv[8];
#pragma unroll
        for (int j = 0; j < 8; j++) outv[j] = fmaxf(acc[i][j] + bo, 0.f);
        float* dst = O + (size_t)o * NVOX + v0 + tx * 8;
        *(float4*)(dst)     = *(const float4*)(outv);
        *(float4*)(dst + 4) = *(const float4*)(outv + 4);
    }
}

// ---------------------------------------------------------------------------
// logits3 GEMM: L[o][v] = sum_c Wc[c][o] * conv1[c][v], M=256 (padded), K=512, N=16384
__global__ __launch_bounds__(256) void k_gemm_logits3(const float* __restrict__ conv1,
                                                      const float* __restrict__ Wc,
                                                      float* __restrict__ L) {
    __shared__ float As[16][128];
    __shared__ float Bs[16][128];
    const int tid = threadIdx.x;
    const int o0 = blockIdx.y * 128;
    const int v0 = blockIdx.x * 128;
    const int ty = tid >> 4, tx = tid & 15;

    float acc[8][8];
#pragma unroll
    for (int i = 0; i < 8; i++)
#pragma unroll
        for (int j = 0; j < 8; j++) acc[i][j] = 0.f;

    for (int ck = 0; ck < 512; ck += 16) {
        __syncthreads();
#pragma unroll
        for (int r = 0; r < 2; ++r) {
            int f = tid + r * 256;
            int c_l = f >> 5, o4 = (f & 31) << 2;
            *(float4*)(&As[c_l][o4]) = *(const float4*)(Wc + ((size_t)(ck + c_l) << 8) + o0 + o4);
        }
#pragma unroll
        for (int r = 0; r < 2; ++r) {
            int f = tid + r * 256;
            int c_l = f >> 5, v4 = (f & 31) << 2;
            *(float4*)(&Bs[c_l][v4]) = *(const float4*)(conv1 + ((size_t)(ck + c_l) << 14) + v0 + v4);
        }
        __syncthreads();
#pragma unroll
        for (int k = 0; k < 16; ++k) {
            float a[8], b[8];
            *(float4*)(a)     = *(const float4*)(&As[k][ty * 8]);
            *(float4*)(a + 4) = *(const float4*)(&As[k][ty * 8 + 4]);
            *(float4*)(b)     = *(const float4*)(&Bs[k][tx * 8]);
            *(float4*)(b + 4) = *(const float4*)(&Bs[k][tx * 8 + 4]);
#pragma unroll
            for (int i = 0; i < 8; i++)
#pragma unroll
                for (int j = 0; j < 8; j++)
                    acc[i][j] = fmaf(a[i], b[j], acc[i][j]);
        }
    }
#pragma unroll
    for (int i = 0; i < 8; i++) {
        float* dst = L + (size_t)(o0 + ty * 8 + i) * NVOX + v0 + tx * 8;
        *(float4*)(dst)     = *(const float4*)(&acc[i][0]);
        *(float4*)(dst + 4) = *(const float4*)(&acc[i][4]);
    }
}

// ---------------------------------------------------------------------------
// sc3[hw*27+a] = mean_t softmax-fg of (L[a]+b[a], L[27+a]+b[27+a])
__global__ void k_sc3(const float* __restrict__ L, const float* __restrict__ b_cls,
                      float* __restrict__ sc3) {
    int i = blockIdx.x * 256 + threadIdx.x;   // 27648
    if (i >= 27 * HW) return;
    int a = i >> 10, hw = i & 1023;
    float b0 = b_cls[a], b1 = b_cls[27 + a];
    const float* L0 = L + (size_t)a * NVOX + hw;
    const float* L1 = L + (size_t)(27 + a) * NVOX + hw;
    float s = 0.f;
    for (int t = 0; t < T_DIM; t++) {
        float x0 = L0[t * HW] + b0, x1 = L1[t * HW] + b1;
        float m = fmaxf(x0, x1);
        float e0 = expf(x0 - m), e1 = expf(x1 - m);
        s += e1 / (e0 + e1);
    }
    sc3[hw * 27 + a] = s * (1.f / 16.f);
}

// dl3[(hw*27+a)*6+d] = mean_t L[54+a*6+d] + b_bbox[a*6+d]
__global__ void k_dl3(const float* __restrict__ L, const float* __restrict__ b_bbox,
                      float* __restrict__ dl3) {
    int i = blockIdx.x * 256 + threadIdx.x;   // 165888
    if (i >= 162 * HW) return;
    int ch = i >> 10, hw = i & 1023;
    const float* Lr = L + (size_t)(54 + ch) * NVOX + hw;
    float s = 0.f;
    for (int t = 0; t < T_DIM; t++) s += Lr[t * HW];
    s = s * (1.f / 16.f) + b_bbox[ch];
    int a = ch / 6, d = ch - a * 6;
    dl3[((size_t)hw * 27 + a) * 6 + d] = s;
}

// feat2[c*1024+hw] = mean_t conv1[c][t*1024+hw]
__global__ void k_feat2(const float* __restrict__ conv1, float* __restrict__ feat2) {
    int i = blockIdx.x * 256 + threadIdx.x;   // 524288
    int c = i >> 10, hw = i & 1023;
    const float* src = conv1 + (size_t)c * NVOX + hw;
    float s = 0.f;
    for (int t = 0; t < T_DIM; t++) s += src[t * HW];
    feat2[i] = s * (1.f / 16.f);
}

// L2[o*1024+hw] (o<54): rows 0..17 = W_cls16, 18..53 = W_bbox16 (no bias)
__global__ void k_gemm2d(const float* __restrict__ feat2, const float* __restrict__ Wcls16,
                         const float* __restrict__ Wbb16, float* __restrict__ L2) {
    int g = blockIdx.x * 256 + threadIdx.x;   // 55296
    int o = g >> 10, hw = g & 1023;
    const float* wrow = (o < 18) ? (Wcls16 + (size_t)o * 512) : (Wbb16 + (size_t)(o - 18) * 512);
    float s = 0.f;
    for (int c = 0; c < 512; c++) s = fmaf(wrow[c], feat2[(size_t)c * HW + hw], s);
    L2[(size_t)o * HW + hw] = s;
}

__global__ void k_sc2(const float* __restrict__ L2, const float* __restrict__ b_cls16,
                      float* __restrict__ sc2) {
    int i = blockIdx.x * 256 + threadIdx.x;   // 9216
    if (i >= 9 * HW) return;
    int a = i >> 10, hw = i & 1023;
    float x0 = L2[(size_t)a * HW + hw] + b_cls16[a];
    float x1 = L2[(size_t)(9 + a) * HW + hw] + b_cls16[9 + a];
    float m = fmaxf(x0, x1);
    float e0 = expf(x0 - m), e1 = expf(x1 - m);
    sc2[hw * 9 + a] = e1 / (e0 + e1);
}

__global__ void k_dl2(const float* __restrict__ L2, const float* __restrict__ b_bbox16,
                      float* __restrict__ dl2) {
    int i = blockIdx.x * 256 + threadIdx.x;   // 36864
    if (i >= 36 * HW) return;
    int ch = i >> 10, hw = i & 1023;
    float v = L2[(size_t)(18 + ch) * HW + hw] + b_bbox16[ch];
    int a = ch >> 2, d = ch & 3;
    dl2[((size_t)hw * 9 + a) * 4 + d] = v;
}

// ---------------------------------------------------------------------------
// monotone map: larger float -> larger unsigned
__device__ __forceinline__ unsigned mapf(float f) {
    unsigned u = __float_as_uint(f);
    return (u & 0x80000000u) ? ~u : (u | 0x80000000u);
}

// proposal: radix-select top-1000 -> bitonic sort -> decode+clip -> bitmask NMS
// blockIdx.x = 0: 3D branch (A=27, nd=3), 1: 2D branch (A=9, nd=2)
__global__ __launch_bounds__(1024) void k_proposal(const float* __restrict__ im_info,
                                                   const float* __restrict__ sc3,
                                                   const float* __restrict__ dl3,
                                                   const float* __restrict__ sc2,
                                                   const float* __restrict__ dl2,
                                                   float* __restrict__ out) {
    const int branch = blockIdx.x;
    const int tid = threadIdx.x;
    const int A = (branch == 0) ? 27 : 9;
    const int nd = (branch == 0) ? 3 : 2;
    const float* scores = (branch == 0) ? sc3 : sc2;
    const float* deltas = (branch == 0) ? dl3 : dl2;
    const int K = PRE_NMS;
    const int ept = A;                 // elements per thread; S = 1024*ept
    const int base = tid * ept;

    __shared__ unsigned hist[256];
    __shared__ unsigned long long keys[1024];
    __shared__ float bx[PRE_NMS][6];
    __shared__ int keep[POST_NMS];
    __shared__ unsigned wsum[16];
    __shared__ unsigned long long alive[16];
    __shared__ int sh_b, sh_next, bcast;

    // ================= radix-select: find mapped value of K-th largest ======
    unsigned prefix = 0;
    int rank = K;                      // rank of target within current subset
    for (int shift = 24; shift >= 0; shift -= 8) {
        if (tid < 256) hist[tid] = 0;
        __syncthreads();
        const unsigned mask_hi = (shift == 24) ? 0u : (0xFFFFFFFFu << (shift + 8));
        for (int j = 0; j < ept; j++) {
            unsigned m = mapf(scores[base + j]);
            if ((m & mask_hi) == prefix)
                atomicAdd(&hist[(m >> shift) & 255], 1u);
        }
        __syncthreads();
        // suffix sums in place: hist[b] := sum_{j>=b} hist[j]
        for (int d = 1; d < 256; d <<= 1) {
            unsigned add = 0;
            if (tid < 256 && tid + d < 256) add = hist[tid + d];
            __syncthreads();
            if (tid < 256) hist[tid] += add;
            __syncthreads();
        }
        // b = max { b : suf[b] >= rank }  (unique winner writes)
        if (tid < 256) {
            bool win = (hist[tid] >= (unsigned)rank) &&
                       (tid == 255 || hist[tid + 1] < (unsigned)rank);
            if (win) { sh_b = tid; sh_next = (tid == 255) ? 0 : (int)hist[tid + 1]; }
        }
        __syncthreads();
        prefix |= (unsigned)sh_b << shift;
        rank -= sh_next;
        __syncthreads();
    }
    const unsigned tau = prefix;       // mapped K-th largest; rank = #eq needed

    // ================= compaction: >tau all, ==tau smallest-index 'rank' ====
    int gt_c = 0, eq_c = 0;
    for (int j = 0; j < ept; j++) {
        unsigned m = mapf(scores[base + j]);
        gt_c += (m > tau);
        eq_c += (m == tau);
    }
    unsigned cnt = ((unsigned)gt_c << 16) | (unsigned)eq_c;
    // block exclusive scan (index order)
    const int lane = tid & 63, wid = tid >> 6;
    unsigned x = cnt;
    for (int d = 1; d < 64; d <<= 1) {
        unsigned y = __shfl_up(x, d);
        if (lane >= d) x += y;
    }
    if (lane == 63) wsum[wid] = x;
    __syncthreads();
    if (wid == 0) {
        unsigned w = (lane < 16) ? wsum[lane] : 0;
        for (int d = 1; d < 16; d <<= 1) {
            unsigned y = __shfl_up(w, d);
            if (lane >= d) w += y;
        }
        if (lane < 16) wsum[lane] = w;
    }
    __syncthreads();
    unsigned excl = x - cnt + (wid ? wsum[wid - 1] : 0);
    const int c1 = (int)(wsum[15] >> 16);          // total count > tau (< K)
    int gi = (int)(excl >> 16);
    int ei = (int)(excl & 0xFFFFu);
    for (int j = 0; j < ept; j++) {
        int idx = base + j;
        unsigned m = mapf(scores[idx]);
        unsigned long long key = ((unsigned long long)m << 32) |
                                 (unsigned)(0xFFFFFFFFu - (unsigned)idx);
        if (m > tau) {
            keys[gi++] = key;
        } else if (m == tau) {
            if (c1 + ei < K) keys[c1 + ei] = key;
            ei++;
        }
    }
    if (tid < 1024 - K) keys[K + tid] = 0;         // pad tail
    __syncthreads();

    // ================= bitonic sort 1024 u64 keys, descending ===============
    for (int k = 2; k <= 1024; k <<= 1) {
        for (int j = k >> 1; j > 0; j >>= 1) {
            int ixj = tid ^ j;
            if (ixj > tid) {
                unsigned long long a = keys[tid], b = keys[ixj];
                bool sw = ((tid & k) == 0) ? (a < b) : (a > b);
                if (sw) { keys[tid] = b; keys[ixj] = a; }
            }
            __syncthreads();
        }
    }

    // ================= decode + clip ========================================
    const float imh = im_info[0], imw = im_info[1];
    if (tid < K) {
        int n = (int)(0xFFFFFFFFu - (unsigned)(keys[tid] & 0xFFFFFFFFull));
        int cell = n / A, a = n - cell * A;
        int hc = cell >> 5, wc = cell & 31;
        int a2 = (branch == 0) ? (a % 9) : a;
        int ri = a2 / 3, si = a2 % 3;
        float w = c_ws[ri] * c_sc[si], h = c_hs[ri] * c_sc[si];
        float lo[3], hi[3], mx[3];
        lo[0] = 7.5f - (w - 1.f) * 0.5f + 16.f * wc;
        hi[0] = 7.5f + (w - 1.f) * 0.5f + 16.f * wc;
        mx[0] = imw - 1.f;
        lo[1] = 7.5f - (h - 1.f) * 0.5f + 16.f * hc;
        hi[1] = 7.5f + (h - 1.f) * 0.5f + 16.f * hc;
        mx[1] = imh - 1.f;
        if (branch == 0) { lo[2] = 0.f; hi[2] = c_depth[a / 9] - 1.f; mx[2] = (float)(T_DIM - 1); }
        const float* dp = deltas + (size_t)n * (2 * nd);
        for (int d = 0; d < nd; d++) {
            float size = hi[d] - lo[d] + 1.f;
            float ctr = lo[d] + 0.5f * (size - 1.f);
            float pctr = dp[d] * size + ctr;
            float psize = expf(dp[nd + d]) * size;
            float pl = pctr - 0.5f * (psize - 1.f);
            float ph = pctr + 0.5f * (psize - 1.f);
            bx[tid][d]      = fminf(fmaxf(pl, 0.f), mx[d]);
            bx[tid][nd + d] = fminf(fmaxf(ph, 0.f), mx[d]);
        }
    }
    // init alive bitmask (bits 0..K-1 set)
    if (tid < 16) alive[tid] = (tid < 15) ? ~0ull : ((1ull << (K - 15 * 64)) - 1);
    __syncthreads();

    // ================= NMS (bitmask) ========================================
    float myb[6]; float myvol = 1.f;
    if (tid < K) {
        for (int d = 0; d < 6; d++) myb[d] = bx[tid][d];
        for (int d = 0; d < nd; d++) myvol *= (myb[nd + d] - myb[d] + 1.f);
    }
    for (int i = 0; i < POST_NMS; ++i) {
        if (tid < 64) {
            unsigned long long wv = (tid < 16) ? alive[tid] : 0ull;
            int cand = wv ? (tid * 64 + __ffsll(wv) - 1) : 0x7fffffff;
#pragma unroll
            for (int off = 32; off; off >>= 1)
                cand = min(cand, __shfl_xor(cand, off));
            if (tid == 0) {
                int m = (cand == 0x7fffffff) ? 0 : cand;
                bcast = m; keep[i] = m;
            }
        }
        __syncthreads();
        int sel = bcast;
        bool s = false;
        if (tid < K) {
            float inter = 1.f, selvol = 1.f;
            for (int d = 0; d < nd; d++) {
                float slo = bx[sel][d], shi = bx[sel][nd + d];
                float l = fmaxf(slo, myb[d]);
                float hh = fminf(shi, myb[nd + d]);
                inter *= fmaxf(hh - l + 1.f, 0.f);
                selvol *= (shi - slo + 1.f);
            }
            float iou = inter / (selvol + myvol - inter);
            s = (iou > NMS_TH) || (tid == sel);
        }
        unsigned long long bal = __ballot(s);
        if (lane == 0 && bal) alive[wid] &= ~bal;
        __syncthreads();
    }

    // ================= write outputs ========================================
    if (tid < POST_NMS) {
        int k = keep[tid];
        if (branch == 0) {
            float* o = out + (size_t)tid * 7;
            o[0] = 0.f;
            for (int d = 0; d < 6; d++) o[1 + d] = bx[k][d];
        } else {
            float* o = out + 128 * 7 + (size_t)tid * 5;
            o[0] = 0.f;
            for (int d = 0; d < 4; d++) o[1 + d] = bx[k][d];
        }
    }
    if (branch == 0 && tid == 0) {
        out[1536] = 0.f; out[1537] = 0.f; out[1538] = 0.f; out[1539] = 0.f;
    }
}

// ---------------------------------------------------------------------------
extern "C" void kernel_launch(void* const* d_in, const int* in_sizes, int n_in,
                              void* d_out, int out_size, void* d_ws, size_t ws_size,
                              hipStream_t stream) {
    (void)in_sizes; (void)n_in; (void)out_size; (void)ws_size;
    const float* base_feat = (const float*)d_in[0];
    const float* im_info   = (const float*)d_in[1];
    const float* W_conv    = (const float*)d_in[4];
    const float* b_conv    = (const float*)d_in[5];
    const float* W_cls     = (const float*)d_in[6];
    const float* b_cls     = (const float*)d_in[7];
    const float* W_bbox    = (const float*)d_in[8];
    const float* b_bbox    = (const float*)d_in[9];
    const float* W_cls16   = (const float*)d_in[10];
    const float* b_cls16   = (const float*)d_in[11];
    const float* W_bbox16  = (const float*)d_in[12];
    const float* b_bbox16  = (const float*)d_in[13];
    float* out = (float*)d_out;

    // workspace layout (bytes, all 16B aligned)
    char* ws = (char*)d_ws;
    size_t off = 0;
    float* Wt     = (float*)(ws + off); off += (size_t)27 * 256 * 512 * 4;
    float* Wcomb  = (float*)(ws + off); off += (size_t)512 * 256 * 4;
    float* conv1  = (float*)(ws + off); off += (size_t)COUT * NVOX * 4;
    float* L3     = (float*)(ws + off); off += (size_t)256 * NVOX * 4;
    float* feat2  = (float*)(ws + off); off += (size_t)512 * HW * 4;
    float* L2     = (float*)(ws + off); off += (size_t)64 * HW * 4;
    float* sc3    = (float*)(ws + off); off += (size_t)27 * HW * 4;
    float* dl3    = (float*)(ws + off); off += (size_t)27 * HW * 6 * 4;
    float* sc2    = (float*)(ws + off); off += (size_t)9 * HW * 4;
    float* dl2    = (float*)(ws + off); off += (size_t)9 * HW * 4 * 4;

    k_transpose_w<<<13824, 256, 0, stream>>>(W_conv, Wt);
    k_build_wcomb<<<512, 256, 0, stream>>>(W_cls, W_bbox, Wcomb);
    {
        dim3 g(NVOX / 128, COUT / 128);
        k_conv3d<<<g, 256, 0, stream>>>(base_feat, Wt, b_conv, conv1);
    }
    {
        dim3 g(NVOX / 128, 2);
        k_gemm_logits3<<<g, 256, 0, stream>>>(conv1, Wcomb, L3);
    }
    k_sc3<<<(27 * HW + 255) / 256, 256, 0, stream>>>(L3, b_cls, sc3);
    k_dl3<<<(162 * HW + 255) / 256, 256, 0, stream>>>(L3, b_bbox, dl3);
    k_feat2<<<(512 * HW) / 256, 256, 0, stream>>>(conv1, feat2);
    k_gemm2d<<<(54 * HW) / 256, 256, 0, stream>>>(feat2, W_cls16, W_bbox16, L2);
    k_sc2<<<(9 * HW + 255) / 256, 256, 0, stream>>>(L2, b_cls16, sc2);
    k_dl2<<<(36 * HW + 255) / 256, 256, 0, stream>>>(L2, b_bbox16, dl2);
    k_proposal<<<2, 1024, 0, stream>>>(im_info, sc3, dl3, sc2, dl2, out);
}

// Round 3
// 2003.436 us; speedup vs baseline: 3.4941x; 1.0669x over previous
//
#include <hip/hip_runtime.h>
#include <hip/hip_bf16.h>
#include <cfloat>
#include <cstdint>

// ---------------------------------------------------------------------------
// RPN pipeline (B=1): conv3d(256->512,3x3x3,SAME)+ReLU -> heads -> proposals
// Shapes: base_feat (1,256,16,32,32), H=W=32, T=16
// Outputs: rois (1,128,7), rois16 (1,128,5), 4 scalar zeros -> 1540 floats
// ---------------------------------------------------------------------------

#define T_DIM 16
#define H_DIM 32
#define W_DIM 32
#define NVOX  (T_DIM*H_DIM*W_DIM)   // 16384
#define HW    (H_DIM*W_DIM)         // 1024
#define CIN   256
#define COUT  512
#define PRE_NMS 1000
#define POST_NMS 128
#define NMS_TH 0.7f

// anchor tables: ratios (0.5,1.0,2.0) -> (ws,hs) = (23,12),(16,16),(11,22); scales 4,8,16
__constant__ float c_ws[3] = {23.f, 16.f, 11.f};
__constant__ float c_hs[3] = {12.f, 16.f, 22.f};
__constant__ float c_sc[3] = {4.f, 8.f, 16.f};
__constant__ float c_depth[3] = {16.f, 8.f, 4.f};

// ---------------------------------------------------------------------------
// Weight transpose: Wt[tap][c][o] = W[o][c][tap]
__global__ void k_transpose_w(const float* __restrict__ W, float* __restrict__ Wt) {
    int i = blockIdx.x * 256 + threadIdx.x;   // over 27*256*512 = 3538944
    int o = i & 511;
    int c = (i >> 9) & 255;
    int tap = i >> 17;
    Wt[i] = W[(o * 256 + c) * 27 + tap];
}

// Wcomb[c][o'] : o'<54 = W_cls[o'][c]; 54..215 = W_bbox[o'-54][c]; 216..255 = 0
__global__ void k_build_wcomb(const float* __restrict__ Wcls, const float* __restrict__ Wbb,
                              float* __restrict__ Wc) {
    int i = blockIdx.x * 256 + threadIdx.x;   // over 512*256
    int o = i & 255;
    int c = i >> 8;
    float v = 0.f;
    if (o < 54) v = Wcls[o * 512 + c];
    else if (o < 216) v = Wbb[(o - 54) * 512 + c];
    Wc[i] = v;
}

// ---------------------------------------------------------------------------
// conv3d as implicit GEMM: O[o][v] = relu(bias[o] + sum_{tap,c} Wt[tap][c][o]*I[c][shift(v,tap)])
// tile 128(o) x 128(v), 256 threads, 8x8 per thread in split-4 layout:
//   rows {ty*4+i, 64+ty*4+i}, cols {tx*4+j, 64+tx*4+j}  -> all LDS ops <=2-way aliased
// BK=32, register-prefetch pipeline (load stage s+1 between barriers).
__global__ __launch_bounds__(256, 2) void k_conv3d(const float* __restrict__ I,
                                                   const float* __restrict__ Wt,
                                                   const float* __restrict__ bias,
                                                   float* __restrict__ O) {
    __shared__ float As[32][128];
    __shared__ float Bs[32][128];
    const int tid = threadIdx.x;
    const int o0 = blockIdx.y * 128;
    const int v0 = blockIdx.x * 128;
    const int ty = tid >> 4, tx = tid & 15;

    float acc[8][8];
#pragma unroll
    for (int i = 0; i < 8; i++)
#pragma unroll
        for (int j = 0; j < 8; j++) acc[i][j] = 0.f;

    // staging assignment (both A and B): lane covers rows (tid>>5)+8r, cols (tid&31)*4
    const int srow = tid >> 5;          // 0..7
    const int scol = (tid & 31) * 4;    // 0..124, float4-contiguous across 32 lanes

    float4 aA[4], bB[4];
    int boff[4]; bool bval[4];

    // per-tap voxel shift tables for the 4 B-columns this lane stages
    auto compute_tap = [&](int tap) {
        const int kt = tap / 9 - 1, kh = (tap / 3) % 3 - 1, kw = tap % 3 - 1;
#pragma unroll
        for (int j = 0; j < 4; ++j) {
            int v = v0 + scol + j;
            int t = v >> 10, h = (v >> 5) & 31, w = v & 31;
            int tt = t + kt, hh = h + kh, ww = w + kw;
            bval[j] = ((unsigned)tt < 16u) && ((unsigned)hh < 32u) && ((unsigned)ww < 32u);
            boff[j] = (tt << 10) + (hh << 5) + ww;
        }
    };
    auto load_stage = [&](int tap, int ck) {
        const float* wp = Wt + ((size_t)(tap * 256 + ck + srow) << 9) + o0 + scol;
#pragma unroll
        for (int r = 0; r < 4; ++r)
            aA[r] = *(const float4*)(wp + (r << 12));           // +8 rows * 512
#pragma unroll
        for (int r = 0; r < 4; ++r) {
            const float* Ic = I + ((size_t)(ck + srow + r * 8) << 14);
            float x0 = bval[0] ? Ic[boff[0]] : 0.f;
            float x1 = bval[1] ? Ic[boff[1]] : 0.f;
            float x2 = bval[2] ? Ic[boff[2]] : 0.f;
            float x3 = bval[3] ? Ic[boff[3]] : 0.f;
            bB[r] = make_float4(x0, x1, x2, x3);
        }
    };

    compute_tap(0);
    load_stage(0, 0);

    for (int s = 0; s < 216; ++s) {                 // 27 taps * 8 ck-steps
#pragma unroll
        for (int r = 0; r < 4; ++r)
            *(float4*)(&As[srow + r * 8][scol]) = aA[r];
#pragma unroll
        for (int r = 0; r < 4; ++r)
            *(float4*)(&Bs[srow + r * 8][scol]) = bB[r];
        __syncthreads();
        int s1 = s + 1;
        if (s1 < 216) {
            int tap1 = s1 >> 3, ck1 = (s1 & 7) << 5;
            if ((s1 & 7) == 0) compute_tap(tap1);
            load_stage(tap1, ck1);
        }
#pragma unroll 4
        for (int k = 0; k < 32; ++k) {
            float a[8], b[8];
            *(float4*)(a)     = *(const float4*)(&As[k][ty * 4]);
            *(float4*)(a + 4) = *(const float4*)(&As[k][64 + ty * 4]);
            *(float4*)(b)     = *(const float4*)(&Bs[k][tx * 4]);
            *(float4*)(b + 4) = *(const float4*)(&Bs[k][64 + tx * 4]);
#pragma unroll
            for (int i = 0; i < 8; i++)
#pragma unroll
                for (int j = 0; j < 8; j++)
                    acc[i][j] = fmaf(a[i], b[j], acc[i][j]);
        }
        __syncthreads();
    }

    // epilogue: bias + relu, split rows/cols
#pragma unroll
    for (int i = 0; i < 8; i++) {
        int orow = (i < 4) ? (ty * 4 + i) : (64 + ty * 4 + (i - 4));
        int o = o0 + orow;
        float bo = bias[o];
        float lo4[4], hi4[4];
#pragma unroll
        for (int j = 0; j < 4; j++) lo4[j] = fmaxf(acc[i][j] + bo, 0.f);
#pragma unroll
        for (int j = 0; j < 4; j++) hi4[j] = fmaxf(acc[i][4 + j] + bo, 0.f);
        float* dst = O + (size_t)o * NVOX + v0;
        *(float4*)(dst + tx * 4)      = *(const float4*)(lo4);
        *(float4*)(dst + 64 + tx * 4) = *(const float4*)(hi4);
    }
}

// ---------------------------------------------------------------------------
// logits3 GEMM: L[o][v] = sum_c Wc[c][o] * conv1[c][v], M=256 (padded), K=512, N=16384
// split-4 fragment layout (conflict-free LDS)
__global__ __launch_bounds__(256) void k_gemm_logits3(const float* __restrict__ conv1,
                                                      const float* __restrict__ Wc,
                                                      float* __restrict__ L) {
    __shared__ float As[16][128];
    __shared__ float Bs[16][128];
    const int tid = threadIdx.x;
    const int o0 = blockIdx.y * 128;
    const int v0 = blockIdx.x * 128;
    const int ty = tid >> 4, tx = tid & 15;

    float acc[8][8];
#pragma unroll
    for (int i = 0; i < 8; i++)
#pragma unroll
        for (int j = 0; j < 8; j++) acc[i][j] = 0.f;

    for (int ck = 0; ck < 512; ck += 16) {
        __syncthreads();
#pragma unroll
        for (int r = 0; r < 2; ++r) {
            int f = tid + r * 256;
            int c_l = f >> 5, o4 = (f & 31) << 2;
            *(float4*)(&As[c_l][o4]) = *(const float4*)(Wc + ((size_t)(ck + c_l) << 8) + o0 + o4);
        }
#pragma unroll
        for (int r = 0; r < 2; ++r) {
            int f = tid + r * 256;
            int c_l = f >> 5, v4 = (f & 31) << 2;
            *(float4*)(&Bs[c_l][v4]) = *(const float4*)(conv1 + ((size_t)(ck + c_l) << 14) + v0 + v4);
        }
        __syncthreads();
#pragma unroll
        for (int k = 0; k < 16; ++k) {
            float a[8], b[8];
            *(float4*)(a)     = *(const float4*)(&As[k][ty * 4]);
            *(float4*)(a + 4) = *(const float4*)(&As[k][64 + ty * 4]);
            *(float4*)(b)     = *(const float4*)(&Bs[k][tx * 4]);
            *(float4*)(b + 4) = *(const float4*)(&Bs[k][64 + tx * 4]);
#pragma unroll
            for (int i = 0; i < 8; i++)
#pragma unroll
                for (int j = 0; j < 8; j++)
                    acc[i][j] = fmaf(a[i], b[j], acc[i][j]);
        }
    }
#pragma unroll
    for (int i = 0; i < 8; i++) {
        int orow = (i < 4) ? (ty * 4 + i) : (64 + ty * 4 + (i - 4));
        float* dst = L + (size_t)(o0 + orow) * NVOX + v0;
        *(float4*)(dst + tx * 4)      = *(const float4*)(&acc[i][0]);
        *(float4*)(dst + 64 + tx * 4) = *(const float4*)(&acc[i][4]);
    }
}

// ---------------------------------------------------------------------------
// sc3[hw*27+a] = mean_t softmax-fg of (L[a]+b[a], L[27+a]+b[27+a])
__global__ void k_sc3(const float* __restrict__ L, const float* __restrict__ b_cls,
                      float* __restrict__ sc3) {
    int i = blockIdx.x * 256 + threadIdx.x;   // 27648
    if (i >= 27 * HW) return;
    int a = i >> 10, hw = i & 1023;
    float b0 = b_cls[a], b1 = b_cls[27 + a];
    const float* L0 = L + (size_t)a * NVOX + hw;
    const float* L1 = L + (size_t)(27 + a) * NVOX + hw;
    float s = 0.f;
    for (int t = 0; t < T_DIM; t++) {
        float x0 = L0[t * HW] + b0, x1 = L1[t * HW] + b1;
        float m = fmaxf(x0, x1);
        float e0 = expf(x0 - m), e1 = expf(x1 - m);
        s += e1 / (e0 + e1);
    }
    sc3[hw * 27 + a] = s * (1.f / 16.f);
}

// dl3[(hw*27+a)*6+d] = mean_t L[54+a*6+d] + b_bbox[a*6+d]
__global__ void k_dl3(const float* __restrict__ L, const float* __restrict__ b_bbox,
                      float* __restrict__ dl3) {
    int i = blockIdx.x * 256 + threadIdx.x;   // 165888
    if (i >= 162 * HW) return;
    int ch = i >> 10, hw = i & 1023;
    const float* Lr = L + (size_t)(54 + ch) * NVOX + hw;
    float s = 0.f;
    for (int t = 0; t < T_DIM; t++) s += Lr[t * HW];
    s = s * (1.f / 16.f) + b_bbox[ch];
    int a = ch / 6, d = ch - a * 6;
    dl3[((size_t)hw * 27 + a) * 6 + d] = s;
}

// feat2[c*1024+hw] = mean_t conv1[c][t*1024+hw]
__global__ void k_feat2(const float* __restrict__ conv1, float* __restrict__ feat2) {
    int i = blockIdx.x * 256 + threadIdx.x;   // 524288
    int c = i >> 10, hw = i & 1023;
    const float* src = conv1 + (size_t)c * NVOX + hw;
    float s = 0.f;
    for (int t = 0; t < T_DIM; t++) s += src[t * HW];
    feat2[i] = s * (1.f / 16.f);
}

// L2[o*1024+hw] (o<54): rows 0..17 = W_cls16, 18..53 = W_bbox16 (no bias)
__global__ void k_gemm2d(const float* __restrict__ feat2, const float* __restrict__ Wcls16,
                         const float* __restrict__ Wbb16, float* __restrict__ L2) {
    int g = blockIdx.x * 256 + threadIdx.x;   // 55296
    int o = g >> 10, hw = g & 1023;
    const float* wrow = (o < 18) ? (Wcls16 + (size_t)o * 512) : (Wbb16 + (size_t)(o - 18) * 512);
    float s = 0.f;
    for (int c = 0; c < 512; c++) s = fmaf(wrow[c], feat2[(size_t)c * HW + hw], s);
    L2[(size_t)o * HW + hw] = s;
}

__global__ void k_sc2(const float* __restrict__ L2, const float* __restrict__ b_cls16,
                      float* __restrict__ sc2) {
    int i = blockIdx.x * 256 + threadIdx.x;   // 9216
    if (i >= 9 * HW) return;
    int a = i >> 10, hw = i & 1023;
    float x0 = L2[(size_t)a * HW + hw] + b_cls16[a];
    float x1 = L2[(size_t)(9 + a) * HW + hw] + b_cls16[9 + a];
    float m = fmaxf(x0, x1);
    float e0 = expf(x0 - m), e1 = expf(x1 - m);
    sc2[hw * 9 + a] = e1 / (e0 + e1);
}

__global__ void k_dl2(const float* __restrict__ L2, const float* __restrict__ b_bbox16,
                      float* __restrict__ dl2) {
    int i = blockIdx.x * 256 + threadIdx.x;   // 36864
    if (i >= 36 * HW) return;
    int ch = i >> 10, hw = i & 1023;
    float v = L2[(size_t)(18 + ch) * HW + hw] + b_bbox16[ch];
    int a = ch >> 2, d = ch & 3;
    dl2[((size_t)hw * 9 + a) * 4 + d] = v;
}

// ---------------------------------------------------------------------------
// monotone map: larger float -> larger unsigned
__device__ __forceinline__ unsigned mapf(float f) {
    unsigned u = __float_as_uint(f);
    return (u & 0x80000000u) ? ~u : (u | 0x80000000u);
}

// proposal: radix-select top-1000 -> bitonic sort -> decode+clip -> bitmask NMS
// blockIdx.x = 0: 3D branch (A=27, nd=3), 1: 2D branch (A=9, nd=2)
__global__ __launch_bounds__(1024) void k_proposal(const float* __restrict__ im_info,
                                                   const float* __restrict__ sc3,
                                                   const float* __restrict__ dl3,
                                                   const float* __restrict__ sc2,
                                                   const float* __restrict__ dl2,
                                                   float* __restrict__ out) {
    const int branch = blockIdx.x;
    const int tid = threadIdx.x;
    const int A = (branch == 0) ? 27 : 9;
    const int nd = (branch == 0) ? 3 : 2;
    const float* scores = (branch == 0) ? sc3 : sc2;
    const float* deltas = (branch == 0) ? dl3 : dl2;
    const int K = PRE_NMS;
    const int ept = A;                 // elements per thread; S = 1024*ept
    const int base = tid * ept;

    __shared__ unsigned hist[256];
    __shared__ unsigned long long keys[1024];
    __shared__ float bx[PRE_NMS][6];
    __shared__ int keep[POST_NMS];
    __shared__ unsigned wsum[16];
    __shared__ unsigned long long alive[16];
    __shared__ int sh_b, sh_next, bcast;

    // ================= radix-select: find mapped value of K-th largest ======
    unsigned prefix = 0;
    int rank = K;                      // rank of target within current subset
    for (int shift = 24; shift >= 0; shift -= 8) {
        if (tid < 256) hist[tid] = 0;
        __syncthreads();
        const unsigned mask_hi = (shift == 24) ? 0u : (0xFFFFFFFFu << (shift + 8));
        for (int j = 0; j < ept; j++) {
            unsigned m = mapf(scores[base + j]);
            if ((m & mask_hi) == prefix)
                atomicAdd(&hist[(m >> shift) & 255], 1u);
        }
        __syncthreads();
        // suffix sums in place: hist[b] := sum_{j>=b} hist[j]
        for (int d = 1; d < 256; d <<= 1) {
            unsigned add = 0;
            if (tid < 256 && tid + d < 256) add = hist[tid + d];
            __syncthreads();
            if (tid < 256) hist[tid] += add;
            __syncthreads();
        }
        // b = max { b : suf[b] >= rank }  (unique winner writes)
        if (tid < 256) {
            bool win = (hist[tid] >= (unsigned)rank) &&
                       (tid == 255 || hist[tid + 1] < (unsigned)rank);
            if (win) { sh_b = tid; sh_next = (tid == 255) ? 0 : (int)hist[tid + 1]; }
        }
        __syncthreads();
        prefix |= (unsigned)sh_b << shift;
        rank -= sh_next;
        __syncthreads();
    }
    const unsigned tau = prefix;       // mapped K-th largest; rank = #eq needed

    // ================= compaction: >tau all, ==tau smallest-index 'rank' ====
    int gt_c = 0, eq_c = 0;
    for (int j = 0; j < ept; j++) {
        unsigned m = mapf(scores[base + j]);
        gt_c += (m > tau);
        eq_c += (m == tau);
    }
    unsigned cnt = ((unsigned)gt_c << 16) | (unsigned)eq_c;
    // block exclusive scan (index order)
    const int lane = tid & 63, wid = tid >> 6;
    unsigned x = cnt;
    for (int d = 1; d < 64; d <<= 1) {
        unsigned y = __shfl_up(x, d);
        if (lane >= d) x += y;
    }
    if (lane == 63) wsum[wid] = x;
    __syncthreads();
    if (wid == 0) {
        unsigned w = (lane < 16) ? wsum[lane] : 0;
        for (int d = 1; d < 16; d <<= 1) {
            unsigned y = __shfl_up(w, d);
            if (lane >= d) w += y;
        }
        if (lane < 16) wsum[lane] = w;
    }
    __syncthreads();
    unsigned excl = x - cnt + (wid ? wsum[wid - 1] : 0);
    const int c1 = (int)(wsum[15] >> 16);          // total count > tau (< K)
    int gi = (int)(excl >> 16);
    int ei = (int)(excl & 0xFFFFu);
    for (int j = 0; j < ept; j++) {
        int idx = base + j;
        unsigned m = mapf(scores[idx]);
        unsigned long long key = ((unsigned long long)m << 32) |
                                 (unsigned)(0xFFFFFFFFu - (unsigned)idx);
        if (m > tau) {
            keys[gi++] = key;
        } else if (m == tau) {
            if (c1 + ei < K) keys[c1 + ei] = key;
            ei++;
        }
    }
    if (tid < 1024 - K) keys[K + tid] = 0;         // pad tail
    __syncthreads();

    // ================= bitonic sort 1024 u64 keys, descending ===============
    for (int k = 2; k <= 1024; k <<= 1) {
        for (int j = k >> 1; j > 0; j >>= 1) {
            int ixj = tid ^ j;
            if (ixj > tid) {
                unsigned long long a = keys[tid], b = keys[ixj];
                bool sw = ((tid & k) == 0) ? (a < b) : (a > b);
                if (sw) { keys[tid] = b; keys[ixj] = a; }
            }
            __syncthreads();
        }
    }

    // ================= decode + clip ========================================
    const float imh = im_info[0], imw = im_info[1];
    if (tid < K) {
        int n = (int)(0xFFFFFFFFu - (unsigned)(keys[tid] & 0xFFFFFFFFull));
        int cell = n / A, a = n - cell * A;
        int hc = cell >> 5, wc = cell & 31;
        int a2 = (branch == 0) ? (a % 9) : a;
        int ri = a2 / 3, si = a2 % 3;
        float w = c_ws[ri] * c_sc[si], h = c_hs[ri] * c_sc[si];
        float lo[3], hi[3], mx[3];
        lo[0] = 7.5f - (w - 1.f) * 0.5f + 16.f * wc;
        hi[0] = 7.5f + (w - 1.f) * 0.5f + 16.f * wc;
        mx[0] = imw - 1.f;
        lo[1] = 7.5f - (h - 1.f) * 0.5f + 16.f * hc;
        hi[1] = 7.5f + (h - 1.f) * 0.5f + 16.f * hc;
        mx[1] = imh - 1.f;
        if (branch == 0) { lo[2] = 0.f; hi[2] = c_depth[a / 9] - 1.f; mx[2] = (float)(T_DIM - 1); }
        const float* dp = deltas + (size_t)n * (2 * nd);
        for (int d = 0; d < nd; d++) {
            float size = hi[d] - lo[d] + 1.f;
            float ctr = lo[d] + 0.5f * (size - 1.f);
            float pctr = dp[d] * size + ctr;
            float psize = expf(dp[nd + d]) * size;
            float pl = pctr - 0.5f * (psize - 1.f);
            float ph = pctr + 0.5f * (psize - 1.f);
            bx[tid][d]      = fminf(fmaxf(pl, 0.f), mx[d]);
            bx[tid][nd + d] = fminf(fmaxf(ph, 0.f), mx[d]);
        }
    }
    // init alive bitmask (bits 0..K-1 set)
    if (tid < 16) alive[tid] = (tid < 15) ? ~0ull : ((1ull << (K - 15 * 64)) - 1);
    __syncthreads();

    // ================= NMS (bitmask) ========================================
    float myb[6]; float myvol = 1.f;
    if (tid < K) {
        for (int d = 0; d < 6; d++) myb[d] = bx[tid][d];
        for (int d = 0; d < nd; d++) myvol *= (myb[nd + d] - myb[d] + 1.f);
    }
    for (int i = 0; i < POST_NMS; ++i) {
        if (tid < 64) {
            unsigned long long wv = (tid < 16) ? alive[tid] : 0ull;
            int cand = wv ? (tid * 64 + __ffsll(wv) - 1) : 0x7fffffff;
#pragma unroll
            for (int off = 32; off; off >>= 1)
                cand = min(cand, __shfl_xor(cand, off));
            if (tid == 0) {
                int m = (cand == 0x7fffffff) ? 0 : cand;
                bcast = m; keep[i] = m;
            }
        }
        __syncthreads();
        int sel = bcast;
        bool s = false;
        if (tid < K) {
            float inter = 1.f, selvol = 1.f;
            for (int d = 0; d < nd; d++) {
                float slo = bx[sel][d], shi = bx[sel][nd + d];
                float l = fmaxf(slo, myb[d]);
                float hh = fminf(shi, myb[nd + d]);
                inter *= fmaxf(hh - l + 1.f, 0.f);
                selvol *= (shi - slo + 1.f);
            }
            float iou = inter / (selvol + myvol - inter);
            s = (iou > NMS_TH) || (tid == sel);
        }
        unsigned long long bal = __ballot(s);
        if (lane == 0 && bal) alive[wid] &= ~bal;
        __syncthreads();
    }

    // ================= write outputs ========================================
    if (tid < POST_NMS) {
        int k = keep[tid];
        if (branch == 0) {
            float* o = out + (size_t)tid * 7;
            o[0] = 0.f;
            for (int d = 0; d < 6; d++) o[1 + d] = bx[k][d];
        } else {
            float* o = out + 128 * 7 + (size_t)tid * 5;
            o[0] = 0.f;
            for (int d = 0; d < 4; d++) o[1 + d] = bx[k][d];
        }
    }
    if (branch == 0 && tid == 0) {
        out[1536] = 0.f; out[1537] = 0.f; out[1538] = 0.f; out[1539] = 0.f;
    }
}

// ---------------------------------------------------------------------------
extern "C" void kernel_launch(void* const* d_in, const int* in_sizes, int n_in,
                              void* d_out, int out_size, void* d_ws, size_t ws_size,
                              hipStream_t stream) {
    (void)in_sizes; (void)n_in; (void)out_size; (void)ws_size;
    const float* base_feat = (const float*)d_in[0];
    const float* im_info   = (const float*)d_in[1];
    const float* W_conv    = (const float*)d_in[4];
    const float* b_conv    = (const float*)d_in[5];
    const float* W_cls     = (const float*)d_in[6];
    const float* b_cls     = (const float*)d_in[7];
    const float* W_bbox    = (const float*)d_in[8];
    const float* b_bbox    = (const float*)d_in[9];
    const float* W_cls16   = (const float*)d_in[10];
    const float* b_cls16   = (const float*)d_in[11];
    const float* W_bbox16  = (const float*)d_in[12];
    const float* b_bbox16  = (const float*)d_in[13];
    float* out = (float*)d_out;

    // workspace layout (bytes, all 16B aligned)
    char* ws = (char*)d_ws;
    size_t off = 0;
    float* Wt     = (float*)(ws + off); off += (size_t)27 * 256 * 512 * 4;
    float* Wcomb  = (float*)(ws + off); off += (size_t)512 * 256 * 4;
    float* conv1  = (float*)(ws + off); off += (size_t)COUT * NVOX * 4;
    float* L3     = (float*)(ws + off); off += (size_t)256 * NVOX * 4;
    float* feat2  = (float*)(ws + off); off += (size_t)512 * HW * 4;
    float* L2     = (float*)(ws + off); off += (size_t)64 * HW * 4;
    float* sc3    = (float*)(ws + off); off += (size_t)27 * HW * 4;
    float* dl3    = (float*)(ws + off); off += (size_t)27 * HW * 6 * 4;
    float* sc2    = (float*)(ws + off); off += (size_t)9 * HW * 4;
    float* dl2    = (float*)(ws + off); off += (size_t)9 * HW * 4 * 4;

    k_transpose_w<<<13824, 256, 0, stream>>>(W_conv, Wt);
    k_build_wcomb<<<512, 256, 0, stream>>>(W_cls, W_bbox, Wcomb);
    {
        dim3 g(NVOX / 128, COUT / 128);
        k_conv3d<<<g, 256, 0, stream>>>(base_feat, Wt, b_conv, conv1);
    }
    {
        dim3 g(NVOX / 128, 2);
        k_gemm_logits3<<<g, 256, 0, stream>>>(conv1, Wcomb, L3);
    }
    k_sc3<<<(27 * HW + 255) / 256, 256, 0, stream>>>(L3, b_cls, sc3);
    k_dl3<<<(162 * HW + 255) / 256, 256, 0, stream>>>(L3, b_bbox, dl3);
    k_feat2<<<(512 * HW) / 256, 256, 0, stream>>>(conv1, feat2);
    k_gemm2d<<<(54 * HW) / 256, 256, 0, stream>>>(feat2, W_cls16, W_bbox16, L2);
    k_sc2<<<(9 * HW + 255) / 256, 256, 0, stream>>>(L2, b_cls16, sc2);
    k_dl2<<<(36 * HW + 255) / 256, 256, 0, stream>>>(L2, b_bbox16, dl2);
    k_proposal<<<2, 1024, 0, stream>>>(im_info, sc3, dl3, sc2, dl2, out);
}

// Round 4
// 1751.421 us; speedup vs baseline: 3.9969x; 1.1439x over previous
//
#include <hip/hip_runtime.h>
#include <hip/hip_bf16.h>
#include <cfloat>
#include <cstdint>

// ---------------------------------------------------------------------------
// RPN pipeline (B=1): conv3d(256->512,3x3x3,SAME)+ReLU -> heads -> proposals
// Shapes: base_feat (1,256,16,32,32), H=W=32, T=16
// Outputs: rois (1,128,7), rois16 (1,128,5), 4 scalar zeros -> 1540 floats
// ---------------------------------------------------------------------------

#define T_DIM 16
#define H_DIM 32
#define W_DIM 32
#define NVOX  (T_DIM*H_DIM*W_DIM)   // 16384
#define HW    (H_DIM*W_DIM)         // 1024
#define CIN   256
#define COUT  512
#define PRE_NMS 1000
#define POST_NMS 128
#define NMS_TH 0.7f

// anchor tables: ratios (0.5,1.0,2.0) -> (ws,hs) = (23,12),(16,16),(11,22); scales 4,8,16
__constant__ float c_ws[3] = {23.f, 16.f, 11.f};
__constant__ float c_hs[3] = {12.f, 16.f, 22.f};
__constant__ float c_sc[3] = {4.f, 8.f, 16.f};
__constant__ float c_depth[3] = {16.f, 8.f, 4.f};

// ---------------------------------------------------------------------------
// Weight transpose: Wt[tap][c][o] = W[o][c][tap]
__global__ void k_transpose_w(const float* __restrict__ W, float* __restrict__ Wt) {
    int i = blockIdx.x * 256 + threadIdx.x;   // over 27*256*512 = 3538944
    int o = i & 511;
    int c = (i >> 9) & 255;
    int tap = i >> 17;
    Wt[i] = W[(o * 256 + c) * 27 + tap];
}

// Wcomb[c][o'] : o'<54 = W_cls[o'][c]; 54..215 = W_bbox[o'-54][c]; 216..255 = 0
__global__ void k_build_wcomb(const float* __restrict__ Wcls, const float* __restrict__ Wbb,
                              float* __restrict__ Wc) {
    int i = blockIdx.x * 256 + threadIdx.x;   // over 512*256
    int o = i & 255;
    int c = i >> 8;
    float v = 0.f;
    if (o < 54) v = Wcls[o * 512 + c];
    else if (o < 216) v = Wbb[(o - 54) * 512 + c];
    Wc[i] = v;
}

// ---------------------------------------------------------------------------
// conv3d as implicit GEMM: O[o][v] = relu(bias[o] + sum_{tap,c} Wt[tap][c][o]*I[c][shift(v,tap)])
// tile 128(o) x 128(v), 256 threads, 8x8 per thread in split-4 layout
// (all LDS ops <=2-way aliased, measured 0 conflicts). BK=32.
// Register double-buffer pipeline with EXPLICIT SCALARS ONLY (no lambdas /
// no local arrays in the staging path -> no scratch spills; round-3 lesson:
// reference-captured arrays forced scratch, VGPR 68 + 370 MB spill traffic).

// per-tap shift/bounds for the 4 staged B columns (t0,h0,w0 shared: scol%4==0)
#define CONV_COMPUTE_TAP(TAP) {                                               \
    int kt_ = (TAP) / 9 - 1, kh_ = ((TAP) / 3) % 3 - 1, kw_ = (TAP) % 3 - 1;  \
    int tt_ = t0 + kt_, hh_ = h0 + kh_;                                       \
    int vth_ = ((unsigned)tt_ < 16u) && ((unsigned)hh_ < 32u);                \
    int wb_ = w0 + kw_;                                                       \
    off0 = (tt_ << 10) + (hh_ << 5) + wb_;                                    \
    off1 = off0 + 1; off2 = off0 + 2; off3 = off0 + 3;                        \
    val0 = vth_ && ((unsigned)wb_ < 32u);                                     \
    val1 = vth_ && ((unsigned)(wb_ + 1) < 32u);                               \
    val2 = vth_ && ((unsigned)(wb_ + 2) < 32u);                               \
    val3 = vth_ && ((unsigned)(wb_ + 3) < 32u);                               \
}

// prefetch one BK=32 stage into registers (A: 4 float4 rows; B: 4 gathered float4)
#define CONV_LOAD(TAP, CK) {                                                  \
    const float* wp_ = Wt + ((size_t)((TAP) * 256 + (CK) + srow) << 9) + o0 + scol; \
    pa0 = *(const float4*)(wp_);                                              \
    pa1 = *(const float4*)(wp_ + (8 << 9));                                   \
    pa2 = *(const float4*)(wp_ + (16 << 9));                                  \
    pa3 = *(const float4*)(wp_ + (24 << 9));                                  \
    const float* ip_ = I + ((size_t)((CK) + srow) << 14);                     \
    pb0 = make_float4(val0 ? ip_[off0] : 0.f, val1 ? ip_[off1] : 0.f,         \
                      val2 ? ip_[off2] : 0.f, val3 ? ip_[off3] : 0.f);        \
    ip_ += (size_t)8 << 14;                                                   \
    pb1 = make_float4(val0 ? ip_[off0] : 0.f, val1 ? ip_[off1] : 0.f,         \
                      val2 ? ip_[off2] : 0.f, val3 ? ip_[off3] : 0.f);        \
    ip_ += (size_t)8 << 14;                                                   \
    pb2 = make_float4(val0 ? ip_[off0] : 0.f, val1 ? ip_[off1] : 0.f,         \
                      val2 ? ip_[off2] : 0.f, val3 ? ip_[off3] : 0.f);        \
    ip_ += (size_t)8 << 14;                                                   \
    pb3 = make_float4(val0 ? ip_[off0] : 0.f, val1 ? ip_[off1] : 0.f,         \
                      val2 ? ip_[off2] : 0.f, val3 ? ip_[off3] : 0.f);        \
}

__global__ __launch_bounds__(256) void k_conv3d(const float* __restrict__ I,
                                                const float* __restrict__ Wt,
                                                const float* __restrict__ bias,
                                                float* __restrict__ O) {
    __shared__ float As[32][128];
    __shared__ float Bs[32][128];
    const int tid = threadIdx.x;
    const int o0 = blockIdx.y * 128;
    const int v0 = blockIdx.x * 128;
    const int ty = tid >> 4, tx = tid & 15;

    float acc[8][8];
#pragma unroll
    for (int i = 0; i < 8; i++)
#pragma unroll
        for (int j = 0; j < 8; j++) acc[i][j] = 0.f;

    // staging assignment: lane covers rows srow+8r, cols scol..scol+3
    const int srow = tid >> 5;          // 0..7
    const int scol = (tid & 31) * 4;    // 0..124

    // voxel decompose for staged columns (shared t/h; w0..w0+3 within a row)
    const int vbase = v0 + scol;
    const int t0 = vbase >> 10, h0 = (vbase >> 5) & 31, w0 = vbase & 31;

    int off0, off1, off2, off3;
    int val0, val1, val2, val3;
    float4 pa0, pa1, pa2, pa3;
    float4 pb0, pb1, pb2, pb3;

    CONV_COMPUTE_TAP(0);
    CONV_LOAD(0, 0);

    for (int s = 0; s < 216; ++s) {                 // 27 taps * 8 ck-steps
        // commit prefetched stage to LDS (writes race-free: previous compute
        // finished at the trailing barrier of iteration s-1)
        *(float4*)(&As[srow][scol])      = pa0;
        *(float4*)(&As[srow + 8][scol])  = pa1;
        *(float4*)(&As[srow + 16][scol]) = pa2;
        *(float4*)(&As[srow + 24][scol]) = pa3;
        *(float4*)(&Bs[srow][scol])      = pb0;
        *(float4*)(&Bs[srow + 8][scol])  = pb1;
        *(float4*)(&Bs[srow + 16][scol]) = pb2;
        *(float4*)(&Bs[srow + 24][scol]) = pb3;
        __syncthreads();
        int s1 = s + 1;
        if (s1 < 216) {
            int tap1 = s1 >> 3, ck1 = (s1 & 7) << 5;
            if ((s1 & 7) == 0) CONV_COMPUTE_TAP(tap1);
            CONV_LOAD(tap1, ck1);
        }
#pragma unroll 4
        for (int k = 0; k < 32; ++k) {
            float a[8], b[8];
            *(float4*)(a)     = *(const float4*)(&As[k][ty * 4]);
            *(float4*)(a + 4) = *(const float4*)(&As[k][64 + ty * 4]);
            *(float4*)(b)     = *(const float4*)(&Bs[k][tx * 4]);
            *(float4*)(b + 4) = *(const float4*)(&Bs[k][64 + tx * 4]);
#pragma unroll
            for (int i = 0; i < 8; i++)
#pragma unroll
                for (int j = 0; j < 8; j++)
                    acc[i][j] = fmaf(a[i], b[j], acc[i][j]);
        }
        __syncthreads();
    }

    // epilogue: bias + relu, split rows/cols
#pragma unroll
    for (int i = 0; i < 8; i++) {
        int orow = (i < 4) ? (ty * 4 + i) : (64 + ty * 4 + (i - 4));
        int o = o0 + orow;
        float bo = bias[o];
        float lo4[4], hi4[4];
#pragma unroll
        for (int j = 0; j < 4; j++) lo4[j] = fmaxf(acc[i][j] + bo, 0.f);
#pragma unroll
        for (int j = 0; j < 4; j++) hi4[j] = fmaxf(acc[i][4 + j] + bo, 0.f);
        float* dst = O + (size_t)o * NVOX + v0;
        *(float4*)(dst + tx * 4)      = *(const float4*)(lo4);
        *(float4*)(dst + 64 + tx * 4) = *(const float4*)(hi4);
    }
}

// ---------------------------------------------------------------------------
// logits3 GEMM: L[o][v] = sum_c Wc[c][o] * conv1[c][v], M=256 (padded), K=512, N=16384
// split-4 fragment layout (conflict-free LDS)
__global__ __launch_bounds__(256) void k_gemm_logits3(const float* __restrict__ conv1,
                                                      const float* __restrict__ Wc,
                                                      float* __restrict__ L) {
    __shared__ float As[16][128];
    __shared__ float Bs[16][128];
    const int tid = threadIdx.x;
    const int o0 = blockIdx.y * 128;
    const int v0 = blockIdx.x * 128;
    const int ty = tid >> 4, tx = tid & 15;

    float acc[8][8];
#pragma unroll
    for (int i = 0; i < 8; i++)
#pragma unroll
        for (int j = 0; j < 8; j++) acc[i][j] = 0.f;

    for (int ck = 0; ck < 512; ck += 16) {
        __syncthreads();
#pragma unroll
        for (int r = 0; r < 2; ++r) {
            int f = tid + r * 256;
            int c_l = f >> 5, o4 = (f & 31) << 2;
            *(float4*)(&As[c_l][o4]) = *(const float4*)(Wc + ((size_t)(ck + c_l) << 8) + o0 + o4);
        }
#pragma unroll
        for (int r = 0; r < 2; ++r) {
            int f = tid + r * 256;
            int c_l = f >> 5, v4 = (f & 31) << 2;
            *(float4*)(&Bs[c_l][v4]) = *(const float4*)(conv1 + ((size_t)(ck + c_l) << 14) + v0 + v4);
        }
        __syncthreads();
#pragma unroll
        for (int k = 0; k < 16; ++k) {
            float a[8], b[8];
            *(float4*)(a)     = *(const float4*)(&As[k][ty * 4]);
            *(float4*)(a + 4) = *(const float4*)(&As[k][64 + ty * 4]);
            *(float4*)(b)     = *(const float4*)(&Bs[k][tx * 4]);
            *(float4*)(b + 4) = *(const float4*)(&Bs[k][64 + tx * 4]);
#pragma unroll
            for (int i = 0; i < 8; i++)
#pragma unroll
                for (int j = 0; j < 8; j++)
                    acc[i][j] = fmaf(a[i], b[j], acc[i][j]);
        }
    }
#pragma unroll
    for (int i = 0; i < 8; i++) {
        int orow = (i < 4) ? (ty * 4 + i) : (64 + ty * 4 + (i - 4));
        float* dst = L + (size_t)(o0 + orow) * NVOX + v0;
        *(float4*)(dst + tx * 4)      = *(const float4*)(&acc[i][0]);
        *(float4*)(dst + 64 + tx * 4) = *(const float4*)(&acc[i][4]);
    }
}

// ---------------------------------------------------------------------------
// sc3[hw*27+a] = mean_t softmax-fg of (L[a]+b[a], L[27+a]+b[27+a])
__global__ void k_sc3(const float* __restrict__ L, const float* __restrict__ b_cls,
                      float* __restrict__ sc3) {
    int i = blockIdx.x * 256 + threadIdx.x;   // 27648
    if (i >= 27 * HW) return;
    int a = i >> 10, hw = i & 1023;
    float b0 = b_cls[a], b1 = b_cls[27 + a];
    const float* L0 = L + (size_t)a * NVOX + hw;
    const float* L1 = L + (size_t)(27 + a) * NVOX + hw;
    float s = 0.f;
    for (int t = 0; t < T_DIM; t++) {
        float x0 = L0[t * HW] + b0, x1 = L1[t * HW] + b1;
        float m = fmaxf(x0, x1);
        float e0 = expf(x0 - m), e1 = expf(x1 - m);
        s += e1 / (e0 + e1);
    }
    sc3[hw * 27 + a] = s * (1.f / 16.f);
}

// dl3[(hw*27+a)*6+d] = mean_t L[54+a*6+d] + b_bbox[a*6+d]
__global__ void k_dl3(const float* __restrict__ L, const float* __restrict__ b_bbox,
                      float* __restrict__ dl3) {
    int i = blockIdx.x * 256 + threadIdx.x;   // 165888
    if (i >= 162 * HW) return;
    int ch = i >> 10, hw = i & 1023;
    const float* Lr = L + (size_t)(54 + ch) * NVOX + hw;
    float s = 0.f;
    for (int t = 0; t < T_DIM; t++) s += Lr[t * HW];
    s = s * (1.f / 16.f) + b_bbox[ch];
    int a = ch / 6, d = ch - a * 6;
    dl3[((size_t)hw * 27 + a) * 6 + d] = s;
}

// feat2[c*1024+hw] = mean_t conv1[c][t*1024+hw]
__global__ void k_feat2(const float* __restrict__ conv1, float* __restrict__ feat2) {
    int i = blockIdx.x * 256 + threadIdx.x;   // 524288
    int c = i >> 10, hw = i & 1023;
    const float* src = conv1 + (size_t)c * NVOX + hw;
    float s = 0.f;
    for (int t = 0; t < T_DIM; t++) s += src[t * HW];
    feat2[i] = s * (1.f / 16.f);
}

// L2[o*1024+hw] (o<54): rows 0..17 = W_cls16, 18..53 = W_bbox16 (no bias)
__global__ void k_gemm2d(const float* __restrict__ feat2, const float* __restrict__ Wcls16,
                         const float* __restrict__ Wbb16, float* __restrict__ L2) {
    int g = blockIdx.x * 256 + threadIdx.x;   // 55296
    int o = g >> 10, hw = g & 1023;
    const float* wrow = (o < 18) ? (Wcls16 + (size_t)o * 512) : (Wbb16 + (size_t)(o - 18) * 512);
    float s = 0.f;
    for (int c = 0; c < 512; c++) s = fmaf(wrow[c], feat2[(size_t)c * HW + hw], s);
    L2[(size_t)o * HW + hw] = s;
}

__global__ void k_sc2(const float* __restrict__ L2, const float* __restrict__ b_cls16,
                      float* __restrict__ sc2) {
    int i = blockIdx.x * 256 + threadIdx.x;   // 9216
    if (i >= 9 * HW) return;
    int a = i >> 10, hw = i & 1023;
    float x0 = L2[(size_t)a * HW + hw] + b_cls16[a];
    float x1 = L2[(size_t)(9 + a) * HW + hw] + b_cls16[9 + a];
    float m = fmaxf(x0, x1);
    float e0 = expf(x0 - m), e1 = expf(x1 - m);
    sc2[hw * 9 + a] = e1 / (e0 + e1);
}

__global__ void k_dl2(const float* __restrict__ L2, const float* __restrict__ b_bbox16,
                      float* __restrict__ dl2) {
    int i = blockIdx.x * 256 + threadIdx.x;   // 36864
    if (i >= 36 * HW) return;
    int ch = i >> 10, hw = i & 1023;
    float v = L2[(size_t)(18 + ch) * HW + hw] + b_bbox16[ch];
    int a = ch >> 2, d = ch & 3;
    dl2[((size_t)hw * 9 + a) * 4 + d] = v;
}

// ---------------------------------------------------------------------------
// monotone map: larger float -> larger unsigned
__device__ __forceinline__ unsigned mapf(float f) {
    unsigned u = __float_as_uint(f);
    return (u & 0x80000000u) ? ~u : (u | 0x80000000u);
}

// proposal: radix-select top-1000 -> bitonic sort -> decode+clip -> bitmask NMS
// blockIdx.x = 0: 3D branch (A=27, nd=3), 1: 2D branch (A=9, nd=2)
__global__ __launch_bounds__(1024) void k_proposal(const float* __restrict__ im_info,
                                                   const float* __restrict__ sc3,
                                                   const float* __restrict__ dl3,
                                                   const float* __restrict__ sc2,
                                                   const float* __restrict__ dl2,
                                                   float* __restrict__ out) {
    const int branch = blockIdx.x;
    const int tid = threadIdx.x;
    const int A = (branch == 0) ? 27 : 9;
    const int nd = (branch == 0) ? 3 : 2;
    const float* scores = (branch == 0) ? sc3 : sc2;
    const float* deltas = (branch == 0) ? dl3 : dl2;
    const int K = PRE_NMS;
    const int ept = A;                 // elements per thread; S = 1024*ept
    const int base = tid * ept;

    __shared__ unsigned hist[256];
    __shared__ unsigned long long keys[1024];
    __shared__ float bx[PRE_NMS][6];
    __shared__ int keep[POST_NMS];
    __shared__ unsigned wsum[16];
    __shared__ unsigned long long alive[16];
    __shared__ int sh_b, sh_next, bcast;

    // ================= radix-select: find mapped value of K-th largest ======
    unsigned prefix = 0;
    int rank = K;                      // rank of target within current subset
    for (int shift = 24; shift >= 0; shift -= 8) {
        if (tid < 256) hist[tid] = 0;
        __syncthreads();
        const unsigned mask_hi = (shift == 24) ? 0u : (0xFFFFFFFFu << (shift + 8));
        for (int j = 0; j < ept; j++) {
            unsigned m = mapf(scores[base + j]);
            if ((m & mask_hi) == prefix)
                atomicAdd(&hist[(m >> shift) & 255], 1u);
        }
        __syncthreads();
        // suffix sums in place: hist[b] := sum_{j>=b} hist[j]
        for (int d = 1; d < 256; d <<= 1) {
            unsigned add = 0;
            if (tid < 256 && tid + d < 256) add = hist[tid + d];
            __syncthreads();
            if (tid < 256) hist[tid] += add;
            __syncthreads();
        }
        // b = max { b : suf[b] >= rank }  (unique winner writes)
        if (tid < 256) {
            bool win = (hist[tid] >= (unsigned)rank) &&
                       (tid == 255 || hist[tid + 1] < (unsigned)rank);
            if (win) { sh_b = tid; sh_next = (tid == 255) ? 0 : (int)hist[tid + 1]; }
        }
        __syncthreads();
        prefix |= (unsigned)sh_b << shift;
        rank -= sh_next;
        __syncthreads();
    }
    const unsigned tau = prefix;       // mapped K-th largest; rank = #eq needed

    // ================= compaction: >tau all, ==tau smallest-index 'rank' ====
    int gt_c = 0, eq_c = 0;
    for (int j = 0; j < ept; j++) {
        unsigned m = mapf(scores[base + j]);
        gt_c += (m > tau);
        eq_c += (m == tau);
    }
    unsigned cnt = ((unsigned)gt_c << 16) | (unsigned)eq_c;
    // block exclusive scan (index order)
    const int lane = tid & 63, wid = tid >> 6;
    unsigned x = cnt;
    for (int d = 1; d < 64; d <<= 1) {
        unsigned y = __shfl_up(x, d);
        if (lane >= d) x += y;
    }
    if (lane == 63) wsum[wid] = x;
    __syncthreads();
    if (wid == 0) {
        unsigned w = (lane < 16) ? wsum[lane] : 0;
        for (int d = 1; d < 16; d <<= 1) {
            unsigned y = __shfl_up(w, d);
            if (lane >= d) w += y;
        }
        if (lane < 16) wsum[lane] = w;
    }
    __syncthreads();
    unsigned excl = x - cnt + (wid ? wsum[wid - 1] : 0);
    const int c1 = (int)(wsum[15] >> 16);          // total count > tau (< K)
    int gi = (int)(excl >> 16);
    int ei = (int)(excl & 0xFFFFu);
    for (int j = 0; j < ept; j++) {
        int idx = base + j;
        unsigned m = mapf(scores[idx]);
        unsigned long long key = ((unsigned long long)m << 32) |
                                 (unsigned)(0xFFFFFFFFu - (unsigned)idx);
        if (m > tau) {
            keys[gi++] = key;
        } else if (m == tau) {
            if (c1 + ei < K) keys[c1 + ei] = key;
            ei++;
        }
    }
    if (tid < 1024 - K) keys[K + tid] = 0;         // pad tail
    __syncthreads();

    // ================= bitonic sort 1024 u64 keys, descending ===============
    for (int k = 2; k <= 1024; k <<= 1) {
        for (int j = k >> 1; j > 0; j >>= 1) {
            int ixj = tid ^ j;
            if (ixj > tid) {
                unsigned long long a = keys[tid], b = keys[ixj];
                bool sw = ((tid & k) == 0) ? (a < b) : (a > b);
                if (sw) { keys[tid] = b; keys[ixj] = a; }
            }
            __syncthreads();
        }
    }

    // ================= decode + clip ========================================
    const float imh = im_info[0], imw = im_info[1];
    if (tid < K) {
        int n = (int)(0xFFFFFFFFu - (unsigned)(keys[tid] & 0xFFFFFFFFull));
        int cell = n / A, a = n - cell * A;
        int hc = cell >> 5, wc = cell & 31;
        int a2 = (branch == 0) ? (a % 9) : a;
        int ri = a2 / 3, si = a2 % 3;
        float w = c_ws[ri] * c_sc[si], h = c_hs[ri] * c_sc[si];
        float lo[3], hi[3], mx[3];
        lo[0] = 7.5f - (w - 1.f) * 0.5f + 16.f * wc;
        hi[0] = 7.5f + (w - 1.f) * 0.5f + 16.f * wc;
        mx[0] = imw - 1.f;
        lo[1] = 7.5f - (h - 1.f) * 0.5f + 16.f * hc;
        hi[1] = 7.5f + (h - 1.f) * 0.5f + 16.f * hc;
        mx[1] = imh - 1.f;
        if (branch == 0) { lo[2] = 0.f; hi[2] = c_depth[a / 9] - 1.f; mx[2] = (float)(T_DIM - 1); }
        const float* dp = deltas + (size_t)n * (2 * nd);
        for (int d = 0; d < nd; d++) {
            float size = hi[d] - lo[d] + 1.f;
            float ctr = lo[d] + 0.5f * (size - 1.f);
            float pctr = dp[d] * size + ctr;
            float psize = expf(dp[nd + d]) * size;
            float pl = pctr - 0.5f * (psize - 1.f);
            float ph = pctr + 0.5f * (psize - 1.f);
            bx[tid][d]      = fminf(fmaxf(pl, 0.f), mx[d]);
            bx[tid][nd + d] = fminf(fmaxf(ph, 0.f), mx[d]);
        }
    }
    // init alive bitmask (bits 0..K-1 set)
    if (tid < 16) alive[tid] = (tid < 15) ? ~0ull : ((1ull << (K - 15 * 64)) - 1);
    __syncthreads();

    // ================= NMS (bitmask) ========================================
    float myb[6]; float myvol = 1.f;
    if (tid < K) {
        for (int d = 0; d < 6; d++) myb[d] = bx[tid][d];
        for (int d = 0; d < nd; d++) myvol *= (myb[nd + d] - myb[d] + 1.f);
    }
    for (int i = 0; i < POST_NMS; ++i) {
        if (tid < 64) {
            unsigned long long wv = (tid < 16) ? alive[tid] : 0ull;
            int cand = wv ? (tid * 64 + __ffsll(wv) - 1) : 0x7fffffff;
#pragma unroll
            for (int off = 32; off; off >>= 1)
                cand = min(cand, __shfl_xor(cand, off));
            if (tid == 0) {
                int m = (cand == 0x7fffffff) ? 0 : cand;
                bcast = m; keep[i] = m;
            }
        }
        __syncthreads();
        int sel = bcast;
        bool s = false;
        if (tid < K) {
            float inter = 1.f, selvol = 1.f;
            for (int d = 0; d < nd; d++) {
                float slo = bx[sel][d], shi = bx[sel][nd + d];
                float l = fmaxf(slo, myb[d]);
                float hh = fminf(shi, myb[nd + d]);
                inter *= fmaxf(hh - l + 1.f, 0.f);
                selvol *= (shi - slo + 1.f);
            }
            float iou = inter / (selvol + myvol - inter);
            s = (iou > NMS_TH) || (tid == sel);
        }
        unsigned long long bal = __ballot(s);
        if (lane == 0 && bal) alive[wid] &= ~bal;
        __syncthreads();
    }

    // ================= write outputs ========================================
    if (tid < POST_NMS) {
        int k = keep[tid];
        if (branch == 0) {
            float* o = out + (size_t)tid * 7;
            o[0] = 0.f;
            for (int d = 0; d < 6; d++) o[1 + d] = bx[k][d];
        } else {
            float* o = out + 128 * 7 + (size_t)tid * 5;
            o[0] = 0.f;
            for (int d = 0; d < 4; d++) o[1 + d] = bx[k][d];
        }
    }
    if (branch == 0 && tid == 0) {
        out[1536] = 0.f; out[1537] = 0.f; out[1538] = 0.f; out[1539] = 0.f;
    }
}

// ---------------------------------------------------------------------------
extern "C" void kernel_launch(void* const* d_in, const int* in_sizes, int n_in,
                              void* d_out, int out_size, void* d_ws, size_t ws_size,
                              hipStream_t stream) {
    (void)in_sizes; (void)n_in; (void)out_size; (void)ws_size;
    const float* base_feat = (const float*)d_in[0];
    const float* im_info   = (const float*)d_in[1];
    const float* W_conv    = (const float*)d_in[4];
    const float* b_conv    = (const float*)d_in[5];
    const float* W_cls     = (const float*)d_in[6];
    const float* b_cls     = (const float*)d_in[7];
    const float* W_bbox    = (const float*)d_in[8];
    const float* b_bbox    = (const float*)d_in[9];
    const float* W_cls16   = (const float*)d_in[10];
    const float* b_cls16   = (const float*)d_in[11];
    const float* W_bbox16  = (const float*)d_in[12];
    const float* b_bbox16  = (const float*)d_in[13];
    float* out = (float*)d_out;

    // workspace layout (bytes, all 16B aligned)
    char* ws = (char*)d_ws;
    size_t off = 0;
    float* Wt     = (float*)(ws + off); off += (size_t)27 * 256 * 512 * 4;
    float* Wcomb  = (float*)(ws + off); off += (size_t)512 * 256 * 4;
    float* conv1  = (float*)(ws + off); off += (size_t)COUT * NVOX * 4;
    float* L3     = (float*)(ws + off); off += (size_t)256 * NVOX * 4;
    float* feat2  = (float*)(ws + off); off += (size_t)512 * HW * 4;
    float* L2     = (float*)(ws + off); off += (size_t)64 * HW * 4;
    float* sc3    = (float*)(ws + off); off += (size_t)27 * HW * 4;
    float* dl3    = (float*)(ws + off); off += (size_t)27 * HW * 6 * 4;
    float* sc2    = (float*)(ws + off); off += (size_t)9 * HW * 4;
    float* dl2    = (float*)(ws + off); off += (size_t)9 * HW * 4 * 4;

    k_transpose_w<<<13824, 256, 0, stream>>>(W_conv, Wt);
    k_build_wcomb<<<512, 256, 0, stream>>>(W_cls, W_bbox, Wcomb);
    {
        dim3 g(NVOX / 128, COUT / 128);
        k_conv3d<<<g, 256, 0, stream>>>(base_feat, Wt, b_conv, conv1);
    }
    {
        dim3 g(NVOX / 128, 2);
        k_gemm_logits3<<<g, 256, 0, stream>>>(conv1, Wcomb, L3);
    }
    k_sc3<<<(27 * HW + 255) / 256, 256, 0, stream>>>(L3, b_cls, sc3);
    k_dl3<<<(162 * HW + 255) / 256, 256, 0, stream>>>(L3, b_bbox, dl3);
    k_feat2<<<(512 * HW) / 256, 256, 0, stream>>>(conv1, feat2);
    k_gemm2d<<<(54 * HW) / 256, 256, 0, stream>>>(feat2, W_cls16, W_bbox16, L2);
    k_sc2<<<(9 * HW + 255) / 256, 256, 0, stream>>>(L2, b_cls16, sc2);
    k_dl2<<<(36 * HW + 255) / 256, 256, 0, stream>>>(L2, b_bbox16, dl2);
    k_proposal<<<2, 1024, 0, stream>>>(im_info, sc3, dl3, sc2, dl2, out);
}